// Round 15
// baseline (308.742 us; speedup 1.0000x reference)
//
#include <hip/hip_runtime.h>
#include <stdint.h>

// Problem sizes (fixed by the reference)
#define NQn 131072
#define NCn 65536
#define En  1048576
// D = 128, HID = 256

typedef __bf16 bf16;
typedef __bf16 bf16x2 __attribute__((ext_vector_type(2)));
typedef __bf16 bf16x4 __attribute__((ext_vector_type(4)));
typedef __bf16 bf16x8 __attribute__((ext_vector_type(8)));
typedef float  f32x4  __attribute__((ext_vector_type(4)));

// ---------------------------------------------------------------------------
// Weight pack: fragment-major layout for MFMA B-operand (see R8 notes).
// ---------------------------------------------------------------------------
__global__ void wtrans_all(
    const float* __restrict__ w0, bf16* __restrict__ t0,
    const float* __restrict__ w1, bf16* __restrict__ t1,
    const float* __restrict__ w2, bf16* __restrict__ t2,
    const float* __restrict__ w3, bf16* __restrict__ t3,
    const float* __restrict__ w4, bf16* __restrict__ t4,
    const float* __restrict__ w5, bf16* __restrict__ t5,
    const float* __restrict__ w6, bf16* __restrict__ t6,
    const float* __restrict__ w7, bf16* __restrict__ t7) {
  const float* W; bf16* T; int K, M;
  switch (blockIdx.y) {
    case 0: W = w0; T = t0; K = 128; M = 128; break;  // Wres_Q
    case 1: W = w1; T = t1; K = 128; M = 128; break;  // Wres_C
    case 2: W = w2; T = t2; K = 128; M = 128; break;  // Wrel_QC
    case 3: W = w3; T = t3; K = 128; M = 128; break;  // Wrel_CQ
    case 4: W = w4; T = t4; K = 256; M = 256; break;  // W1_Q
    case 5: W = w5; T = t5; K = 256; M = 256; break;  // W1_C
    case 6: W = w6; T = t6; K = 256; M = 128; break;  // W2_Q
    default: W = w7; T = t7; K = 256; M = 128; break; // W2_C
  }
  int t = blockIdx.x * 256 + threadIdx.x;
  if (t >= K * M) return;
  int KB = K >> 5;
  int frag = t >> 9, within = t & 511;
  int lane = within >> 3, j = within & 7;
  int mb = frag / KB, kb = frag % KB;
  int m = mb * 16 + (lane & 15);
  int k = kb * 32 + (lane >> 4) * 8 + j;
  T[t] = (bf16)W[k * M + m];
}

// ---------------------------------------------------------------------------
// dual_gemm2: merged Q+C. One H read -> proj = LN(H)@Wres AND
// xn = (H@Wrel)*deg^-1/2. 64-row tile, 4 waves, 32KB LDS.
// Epilogue staged through LDS -> bf16x8 coalesced stores.
// ---------------------------------------------------------------------------
__global__ __launch_bounds__(256, 5) void dual_gemm2(
    const float* __restrict__ HQ, const float* __restrict__ lngQ,
    const float* __restrict__ lnbQ, const bf16* __restrict__ WresQ,
    const bf16* __restrict__ WrelQ, const float* __restrict__ degQ,
    bf16* __restrict__ projQ, bf16* __restrict__ xnQ, int splitQ,
    const float* __restrict__ HC, const float* __restrict__ lngC,
    const float* __restrict__ lnbC, const bf16* __restrict__ WresC,
    const bf16* __restrict__ WrelC, const float* __restrict__ degC,
    bf16* __restrict__ projC, bf16* __restrict__ xnC) {
  __shared__ __align__(16) unsigned char lds[32768];
  const float *H, *lng, *lnb, *degsrc;
  const bf16 *Wres, *Wrel;
  bf16 *proj, *xn;
  int bid = blockIdx.x;
  if (bid < splitQ) {
    H = HQ; lng = lngQ; lnb = lnbQ; Wres = WresQ; Wrel = WrelQ;
    degsrc = degQ; proj = projQ; xn = xnQ;
  } else {
    bid -= splitQ;
    H = HC; lng = lngC; lnb = lnbC; Wres = WresC; Wrel = WrelC;
    degsrc = degC; proj = projC; xn = xnC;
  }
  const int tid = threadIdx.x;
  const int row0 = bid * 64;
  const int wid = tid >> 6, lane = tid & 63;
  const int wrow = (wid >> 1) * 32, wcol = (wid & 1) * 64;

  // stage: read H f32, LN inline, write lnh@0, hb@16384 (rows 256B, swizzled)
  #pragma unroll
  for (int it = 0; it < 8; ++it) {
    int lin = it * 256 + tid;
    int r = lin >> 5;
    int c = (lin & 31) * 4;
    float4 v = *(const float4*)(H + (size_t)(row0 + r) * 128 + c);
    float s = v.x + v.y + v.z + v.w;
    #pragma unroll
    for (int o = 16; o; o >>= 1) s += __shfl_xor(s, o, 64);
    float mean = s * (1.0f / 128.0f);
    float d0 = v.x - mean, d1 = v.y - mean, d2 = v.z - mean, d3 = v.w - mean;
    float q = d0 * d0 + d1 * d1 + d2 * d2 + d3 * d3;
    #pragma unroll
    for (int o = 16; o; o >>= 1) q += __shfl_xor(q, o, 64);
    float rsv = rsqrtf(q * (1.0f / 128.0f) + 1e-5f);
    float4 gg = *(const float4*)(lng + c);
    float4 bb = *(const float4*)(lnb + c);
    bf16x4 w;
    w[0] = (bf16)(d0 * rsv * gg.x + bb.x);
    w[1] = (bf16)(d1 * rsv * gg.y + bb.y);
    w[2] = (bf16)(d2 * rsv * gg.z + bb.z);
    w[3] = (bf16)(d3 * rsv * gg.w + bb.w);
    int off = r * 256 + ((c * 2) ^ ((r & 7) << 4));
    *(bf16x4*)(lds + off) = w;
    bf16x4 rw;
    rw[0] = (bf16)v.x; rw[1] = (bf16)v.y; rw[2] = (bf16)v.z; rw[3] = (bf16)v.w;
    *(bf16x4*)(lds + 16384 + off) = rw;
  }
  __syncthreads();

  const int rloc = wrow + (lane >> 4) * 4;
  const int cloc = wcol + (lane & 15);

  // pass 0: proj = lnh @ Wres
  {
    f32x4 acc[2][4] = {};
    #pragma unroll
    for (int kk = 0; kk < 4; ++kk) {
      const int kb = kk * 64 + (lane >> 4) * 16;
      bf16x8 af[2], bfv[4];
      #pragma unroll
      for (int fc = 0; fc < 4; ++fc) {
        int cblk = (wid & 1) * 4 + fc;
        bfv[fc] = *(const bf16x8*)(Wres + ((size_t)(cblk * 4 + kk) * 64 + lane) * 8);
      }
      #pragma unroll
      for (int fr = 0; fr < 2; ++fr) {
        int ar = wrow + fr * 16 + (lane & 15);
        af[fr] = *(const bf16x8*)(lds + ar * 256 + (kb ^ ((ar & 7) << 4)));
      }
      #pragma unroll
      for (int fr = 0; fr < 2; ++fr)
        #pragma unroll
        for (int fc = 0; fc < 4; ++fc)
          acc[fr][fc] = __builtin_amdgcn_mfma_f32_16x16x32_bf16(
              af[fr], bfv[fc], acc[fr][fc], 0, 0, 0);
    }
    __syncthreads();
    #pragma unroll
    for (int fr = 0; fr < 2; ++fr)
      #pragma unroll
      for (int fc = 0; fc < 4; ++fc)
        #pragma unroll
        for (int r = 0; r < 4; ++r) {
          int row = rloc + fr * 16 + r;
          int colb = (cloc + fc * 16) * 2;
          *(bf16*)(lds + row * 256 + (colb ^ ((row & 7) << 4))) =
              (bf16)acc[fr][fc][r];
        }
  }

  // pass 1: xn = (hb @ Wrel) * invsqrt(deg)
  {
    f32x4 acc[2][4] = {};
    #pragma unroll
    for (int kk = 0; kk < 4; ++kk) {
      const int kb = kk * 64 + (lane >> 4) * 16;
      bf16x8 af[2], bfv[4];
      #pragma unroll
      for (int fc = 0; fc < 4; ++fc) {
        int cblk = (wid & 1) * 4 + fc;
        bfv[fc] = *(const bf16x8*)(Wrel + ((size_t)(cblk * 4 + kk) * 64 + lane) * 8);
      }
      #pragma unroll
      for (int fr = 0; fr < 2; ++fr) {
        int ar = wrow + fr * 16 + (lane & 15);
        af[fr] = *(const bf16x8*)(lds + 16384 + ar * 256 + (kb ^ ((ar & 7) << 4)));
      }
      #pragma unroll
      for (int fr = 0; fr < 2; ++fr)
        #pragma unroll
        for (int fc = 0; fc < 4; ++fc)
          acc[fr][fc] = __builtin_amdgcn_mfma_f32_16x16x32_bf16(
              af[fr], bfv[fc], acc[fr][fc], 0, 0, 0);
    }
    __syncthreads();
    #pragma unroll
    for (int fr = 0; fr < 2; ++fr) {
      float rs[4];
      #pragma unroll
      for (int r = 0; r < 4; ++r) {
        float dv = degsrc[row0 + rloc + fr * 16 + r];
        rs[r] = dv > 0.f ? rsqrtf(dv) : 0.f;
      }
      #pragma unroll
      for (int fc = 0; fc < 4; ++fc)
        #pragma unroll
        for (int r = 0; r < 4; ++r) {
          int row = rloc + fr * 16 + r;
          int colb = (cloc + fc * 16) * 2;
          *(bf16*)(lds + 16384 + row * 256 + (colb ^ ((row & 7) << 4))) =
              (bf16)(acc[fr][fc][r] * rs[r]);
        }
    }
  }
  __syncthreads();

  // coalesced stores: 16KB proj tile + 16KB xn tile, bf16x8 per chunk
  #pragma unroll
  for (int it = 0; it < 8; ++it) {
    int lin = it * 256 + tid;
    int pb = (lin < 1024) ? 0 : 16384;
    bf16* dst = (lin < 1024) ? proj : xn;
    int chunk = lin & 1023;
    int r = chunk >> 4;
    int cb = (chunk & 15) * 16;
    bf16x8 v = *(const bf16x8*)(lds + pb + r * 256 + (cb ^ ((r & 7) << 4)));
    *(bf16x8*)((char*)(dst + (size_t)(row0 + r) * 128) + cb) = v;
  }
}

// ---------------------------------------------------------------------------
// mlp_fused2: merged Q+C. out = proj + GELU([proj|msg]@W1+b1)@W2 + b2.
// 64-row tile, 4 waves, 32KB LDS. (256,4): VGPR 64 needed — (256,5) spills
// (R13). A/h panel swizzle (r&15)<<4 (16 distinct slots for 16 rows/quarter-
// wave; (r&7) left 2-way conflicts, R14: 2.36M). f32 out staged via LDS ->
// float4 coalesced stores + vectorized bf16x4 residual reads (R9 lesson).
// ---------------------------------------------------------------------------
__global__ __launch_bounds__(256, 4) void mlp_fused2(
    const bf16* __restrict__ projQ, const bf16* __restrict__ msgQ,
    const bf16* __restrict__ W1Q, const float* __restrict__ b1Q,
    const bf16* __restrict__ W2Q, const float* __restrict__ b2Q,
    float* __restrict__ outQ, int splitQ,
    const bf16* __restrict__ projC, const bf16* __restrict__ msgC,
    const bf16* __restrict__ W1C, const float* __restrict__ b1C,
    const bf16* __restrict__ W2C, const float* __restrict__ b2C,
    float* __restrict__ outC) {
  __shared__ __align__(16) unsigned char lds[32768];
  const bf16 *proj, *msg, *W1p, *W2p;
  const float *b1, *b2;
  float* out;
  int bid = blockIdx.x;
  if (bid < splitQ) {
    proj = projQ; msg = msgQ; W1p = W1Q; b1 = b1Q; W2p = W2Q; b2 = b2Q; out = outQ;
  } else {
    bid -= splitQ;
    proj = projC; msg = msgC; W1p = W1C; b1 = b1C; W2p = W2C; b2 = b2C; out = outC;
  }
  const int tid = threadIdx.x;
  const int row0 = bid * 64;
  const int wid = tid >> 6, lane = tid & 63;

  // stage A = [proj | msg], 64 rows x 512B, swizzle (r&15)<<4
  #pragma unroll
  for (int it = 0; it < 8; ++it) {
    int lin = it * 256 + tid;
    int r = lin >> 5;
    int cb = (lin & 31) * 16;
    const bf16* src = (cb < 256) ? (proj + (size_t)(row0 + r) * 128)
                                 : (msg + (size_t)(row0 + r) * 128 - 128);
    bf16x8 v = *(const bf16x8*)((const char*)src + cb);
    *(bf16x8*)(lds + r * 512 + (cb ^ ((r & 15) << 4))) = v;
  }
  __syncthreads();

  // phase 1: h[64][256] = A @ W1 (K=256); wave w covers cols w*64..+63
  f32x4 acc1[4][4] = {};
  #pragma unroll
  for (int kk = 0; kk < 8; ++kk) {
    const int kb = kk * 64 + (lane >> 4) * 16;
    bf16x8 af[4], bfv[4];
    #pragma unroll
    for (int fc = 0; fc < 4; ++fc) {
      int cblk = wid * 4 + fc;
      bfv[fc] = *(const bf16x8*)(W1p + ((size_t)(cblk * 8 + kk) * 64 + lane) * 8);
    }
    #pragma unroll
    for (int fr = 0; fr < 4; ++fr) {
      int ar = fr * 16 + (lane & 15);
      af[fr] = *(const bf16x8*)(lds + ar * 512 + (kb ^ ((ar & 15) << 4)));
    }
    #pragma unroll
    for (int fr = 0; fr < 4; ++fr)
      #pragma unroll
      for (int fc = 0; fc < 4; ++fc)
        acc1[fr][fc] = __builtin_amdgcn_mfma_f32_16x16x32_bf16(
            af[fr], bfv[fc], acc1[fr][fc], 0, 0, 0);
  }
  __syncthreads();   // all A reads done -> safe to overwrite with h

  // GELU + b1 -> h panel (64 rows x 512B, same swizzle)
  {
    const int rb = (lane >> 4) * 4;
    const int cb0 = wid * 64 + (lane & 15);
    #pragma unroll
    for (int fc = 0; fc < 4; ++fc) {
      int col = cb0 + fc * 16;
      float bv = b1[col];
      #pragma unroll
      for (int fr = 0; fr < 4; ++fr) {
        #pragma unroll
        for (int r = 0; r < 4; ++r) {
          int row = rb + fr * 16 + r;
          float x = acc1[fr][fc][r] + bv;
          float u2 = 1.5957691216057308f * (x + 0.044715f * x * x * x);
          float e = __expf(u2);
          x = 0.5f * x * (1.f + (1.f - 2.f / (e + 1.f)));
          *(bf16*)(lds + row * 512 + ((col * 2) ^ ((row & 15) << 4))) = (bf16)x;
        }
      }
    }
  }
  __syncthreads();

  // phase 2: acc2 = h @ W2; wave grid 2x2 (32x64)
  const int wrow2 = (wid >> 1) * 32;
  const int wcol2 = (wid & 1) * 64;
  f32x4 acc2[2][4] = {};
  #pragma unroll
  for (int kk = 0; kk < 8; ++kk) {
    const int kb = kk * 64 + (lane >> 4) * 16;
    bf16x8 af[2], bfv[4];
    #pragma unroll
    for (int fc = 0; fc < 4; ++fc) {
      int cblk = (wid & 1) * 4 + fc;
      bfv[fc] = *(const bf16x8*)(W2p + ((size_t)(cblk * 8 + kk) * 64 + lane) * 8);
    }
    #pragma unroll
    for (int fr = 0; fr < 2; ++fr) {
      int ar = wrow2 + fr * 16 + (lane & 15);
      af[fr] = *(const bf16x8*)(lds + ar * 512 + (kb ^ ((ar & 15) << 4)));
    }
    #pragma unroll
    for (int fr = 0; fr < 2; ++fr)
      #pragma unroll
      for (int fc = 0; fc < 4; ++fc)
        acc2[fr][fc] = __builtin_amdgcn_mfma_f32_16x16x32_bf16(
            af[fr], bfv[fc], acc2[fr][fc], 0, 0, 0);
  }
  __syncthreads();   // all h reads done -> reuse LDS as f32 out tile

  // stage acc2+b2 into f32 LDS tile (64 rows x 512B, swizzle (row&15)<<4)
  {
    const int rbase = wrow2 + (lane >> 4) * 4;
    const int cbase = wcol2 + (lane & 15);
    #pragma unroll
    for (int fc = 0; fc < 4; ++fc) {
      int col = cbase + fc * 16;
      float bv = b2[col];
      #pragma unroll
      for (int fr = 0; fr < 2; ++fr)
        #pragma unroll
        for (int r = 0; r < 4; ++r) {
          int row = rbase + fr * 16 + r;
          *(float*)(lds + row * 512 + ((col * 4) ^ ((row & 15) << 4))) =
              acc2[fr][fc][r] + bv;
        }
    }
  }
  __syncthreads();

  // coalesced out: float4 from LDS + bf16x4 proj residual + float4 store
  #pragma unroll
  for (int it = 0; it < 8; ++it) {
    int lin = it * 256 + tid;          // 2048 x 16B chunks
    int r = lin >> 5;
    int cb = (lin & 31) * 16;          // byte col in f32 row
    float4 v = *(const float4*)(lds + r * 512 + (cb ^ ((r & 15) << 4)));
    int col = cb >> 2;                 // f32 col index
    bf16x4 p = *(const bf16x4*)(proj + (size_t)(row0 + r) * 128 + col);
    v.x += (float)p[0]; v.y += (float)p[1];
    v.z += (float)p[2]; v.w += (float)p[3];
    *(float4*)(out + (size_t)(row0 + r) * 128 + col) = v;
  }
}

// ---------------------------------------------------------------------------
// Bucket histogram + scan (bucket = 128 dst rows). bcnt: [512 QC][1024 CQ]
// ---------------------------------------------------------------------------
__global__ __launch_bounds__(256) void bucket_hist(
    const float* __restrict__ degQC, const float* __restrict__ degCQ,
    int* __restrict__ bcnt) {
  int w = (blockIdx.x * 256 + threadIdx.x) >> 6;
  int lane = threadIdx.x & 63;
  const float* deg = (w < 512) ? (degQC + (size_t)w * 128)
                               : (degCQ + (size_t)(w - 512) * 128);
  float s = deg[lane] + deg[lane + 64];
  #pragma unroll
  for (int o = 32; o; o >>= 1) s += __shfl_xor(s, o, 64);
  if (lane == 0) bcnt[w] = (int)(s + 0.5f);
}

__global__ __launch_bounds__(1024) void bucket_scan(
    const int* __restrict__ bcnt,
    int* __restrict__ baseQC, int* __restrict__ gcurQC,
    int* __restrict__ baseCQ, int* __restrict__ gcurCQ) {
  __shared__ int ss[1024];
  const int t = threadIdx.x;
  int v = (t < 512) ? bcnt[t] : 0;
  ss[t] = v;
  __syncthreads();
  for (int o = 1; o < 1024; o <<= 1) {
    int x = (t >= o) ? ss[t - o] : 0;
    __syncthreads();
    ss[t] += x;
    __syncthreads();
  }
  if (t < 512) { int e = ss[t] - v; baseQC[t] = e; gcurQC[t] = e; }
  if (t == 0) baseQC[512] = En;
  __syncthreads();
  int v2 = bcnt[512 + t];
  ss[t] = v2;
  __syncthreads();
  for (int o = 1; o < 1024; o <<= 1) {
    int x = (t >= o) ? ss[t - o] : 0;
    __syncthreads();
    ss[t] += x;
    __syncthreads();
  }
  { int e = ss[t] - v2; baseCQ[t] = e; gcurCQ[t] = e; }
  if (t == 0) baseCQ[1024] = En;
}

// ---------------------------------------------------------------------------
// bucketA2: merged Q+C edge partition (bucket = dst>>7).
// ---------------------------------------------------------------------------
#define CHUNK 4096

__global__ __launch_bounds__(256) void bucketA2(
    const int* __restrict__ esrcQ, const int* __restrict__ edstQ,
    int* __restrict__ gcurQ, uint2* __restrict__ ebufQ, int splitQ,
    const int* __restrict__ esrcC, const int* __restrict__ edstC,
    int* __restrict__ gcurC, uint2* __restrict__ ebufC) {
  constexpr int NB = 1024;
  __shared__ int lcount[NB], lexcl[NB], lbase[NB], lofs[NB];
  __shared__ int ss[256];
  __shared__ uint2 stage[CHUNK];
  const int* esrc; const int* edst; int* gcur; uint2* ebuf; int nb;
  int bid = blockIdx.x;
  if (bid < splitQ) { esrc = esrcQ; edst = edstQ; gcur = gcurQ; ebuf = ebufQ; nb = 512; }
  else { bid -= splitQ; esrc = esrcC; edst = edstC; gcur = gcurC; ebuf = ebufC; nb = 1024; }
  const int t = threadIdx.x;
  for (int b = t; b < NB; b += 256) lcount[b] = 0;
  __syncthreads();
  const int e0 = bid * CHUNK;
  uint2 ed[16];
  #pragma unroll
  for (int j = 0; j < 16; ++j) {
    int e = e0 + j * 256 + t;
    ed[j].x = (unsigned)esrc[e];
    ed[j].y = (unsigned)edst[e];
    atomicAdd(&lcount[ed[j].y >> 7], 1);
  }
  __syncthreads();
  int c[4]; int mysum = 0;
  #pragma unroll
  for (int j = 0; j < 4; ++j) { c[j] = lcount[t * 4 + j]; mysum += c[j]; }
  ss[t] = mysum;
  __syncthreads();
  for (int o = 1; o < 256; o <<= 1) {
    int x = (t >= o) ? ss[t - o] : 0;
    __syncthreads();
    ss[t] += x;
    __syncthreads();
  }
  int run = ss[t] - mysum;
  #pragma unroll
  for (int j = 0; j < 4; ++j) { lexcl[t * 4 + j] = run; run += c[j]; }
  __syncthreads();
  for (int b = t; b < NB; b += 256) {
    lbase[b] = (b < nb && lcount[b]) ? atomicAdd(&gcur[b], lcount[b]) : 0;
    lofs[b]  = lexcl[b];
  }
  __syncthreads();
  #pragma unroll
  for (int j = 0; j < 16; ++j) {
    int b = ed[j].y >> 7;
    int p = atomicAdd(&lofs[b], 1);
    stage[p] = ed[j];
  }
  __syncthreads();
  for (int i = t; i < CHUNK; i += 256) {
    uint2 v = stage[i];
    int b = v.y >> 7;
    ebuf[lbase[b] + (i - lexcl[b])] = v;
  }
}

// ---------------------------------------------------------------------------
// bucketB22: merged Q+C. Per-bucket deg-scan -> offs; fill csr via INT LDS
// atomics (csr window contiguous, L2-hot).
// ---------------------------------------------------------------------------
__global__ __launch_bounds__(256) void bucketB22(
    const uint2* __restrict__ ebufQ, const int* __restrict__ bbaseQ,
    const float* __restrict__ degQ, int* __restrict__ offsQ,
    int* __restrict__ csrQ, int splitQ,
    const uint2* __restrict__ ebufC, const int* __restrict__ bbaseC,
    const float* __restrict__ degC, int* __restrict__ offsC,
    int* __restrict__ csrC) {
  __shared__ int sdeg[128];
  __shared__ int lcur[128];
  const uint2* ebuf; const int* bbase; const float* degdst; int* offs; int* csr;
  int b = blockIdx.x;
  if (b < splitQ) { ebuf = ebufQ; bbase = bbaseQ; degdst = degQ; offs = offsQ; csr = csrQ; }
  else { b -= splitQ; ebuf = ebufC; bbase = bbaseC; degdst = degC; offs = offsC; csr = csrC; }
  const int t = threadIdx.x;
  const int base = bbase[b], end = bbase[b + 1];
  int myv = 0;
  if (t < 128) {
    myv = (int)(degdst[(size_t)b * 128 + t] + 0.5f);
    sdeg[t] = myv;
  }
  __syncthreads();
  for (int o = 1; o < 128; o <<= 1) {
    int x = (t < 128 && t >= o) ? sdeg[t - o] : 0;
    __syncthreads();
    if (t < 128) sdeg[t] += x;
    __syncthreads();
  }
  if (t < 128) {
    int excl = sdeg[t] - myv;
    lcur[t] = excl;
    offs[(size_t)b * 128 + t] = base + excl;
  }
  __syncthreads();
  for (int i = base + t; i < end; i += 256) {
    uint2 v = ebuf[i];
    int p = atomicAdd(&lcur[v.y & 127], 1);
    csr[base + p] = (int)v.x;
  }
}

// ---------------------------------------------------------------------------
// gather_one: one relation. One wave per dst row, half-wave pairing,
// 8 edges in flight.
// ---------------------------------------------------------------------------
__global__ __launch_bounds__(256) void gather_one(
    const bf16* __restrict__ Xn, const int* __restrict__ csr,
    const int* __restrict__ offs, const float* __restrict__ degdst,
    const float* __restrict__ gate, bf16* __restrict__ msg) {
  int d = blockIdx.x * 4 + (threadIdx.x >> 6);
  int lane = threadIdx.x & 63;
  int half = lane >> 5, sl = lane & 31;
  float dv = degdst[d];
  int cnt = (int)(dv + 0.5f);
  int start = offs[d];
  float a0 = 0.f, a1 = 0.f, a2 = 0.f, a3 = 0.f;
  int i = 0;
  for (; i + 8 <= cnt; i += 8) {
    int s0 = csr[start + i + half * 4 + 0];
    int s1 = csr[start + i + half * 4 + 1];
    int s2 = csr[start + i + half * 4 + 2];
    int s3 = csr[start + i + half * 4 + 3];
    bf16x4 v0 = *(const bf16x4*)(Xn + (size_t)s0 * 128 + sl * 4);
    bf16x4 v1 = *(const bf16x4*)(Xn + (size_t)s1 * 128 + sl * 4);
    bf16x4 v2 = *(const bf16x4*)(Xn + (size_t)s2 * 128 + sl * 4);
    bf16x4 v3 = *(const bf16x4*)(Xn + (size_t)s3 * 128 + sl * 4);
    a0 += (float)v0[0] + (float)v1[0] + (float)v2[0] + (float)v3[0];
    a1 += (float)v0[1] + (float)v1[1] + (float)v2[1] + (float)v3[1];
    a2 += (float)v0[2] + (float)v1[2] + (float)v2[2] + (float)v3[2];
    a3 += (float)v0[3] + (float)v1[3] + (float)v2[3] + (float)v3[3];
  }
  for (; i + 2 <= cnt; i += 2) {
    int s0 = csr[start + i + half];
    bf16x4 v0 = *(const bf16x4*)(Xn + (size_t)s0 * 128 + sl * 4);
    a0 += (float)v0[0]; a1 += (float)v0[1];
    a2 += (float)v0[2]; a3 += (float)v0[3];
  }
  if (i < cnt && half == 0) {
    int s0 = csr[start + i];
    bf16x4 v0 = *(const bf16x4*)(Xn + (size_t)s0 * 128 + sl * 4);
    a0 += (float)v0[0]; a1 += (float)v0[1];
    a2 += (float)v0[2]; a3 += (float)v0[3];
  }
  a0 += __shfl_xor(a0, 32, 64);
  a1 += __shfl_xor(a1, 32, 64);
  a2 += __shfl_xor(a2, 32, 64);
  a3 += __shfl_xor(a3, 32, 64);
  if (half == 0) {
    float sc = (dv > 0.f ? rsqrtf(dv) : 0.f) * gate[0];
    bf16x4 r;
    r[0] = (bf16)(a0 * sc); r[1] = (bf16)(a1 * sc);
    r[2] = (bf16)(a2 * sc); r[3] = (bf16)(a3 * sc);
    *(bf16x4*)(msg + (size_t)d * 128 + sl * 4) = r;
  }
}

// ---------------------------------------------------------------------------
extern "C" void kernel_launch(void* const* d_in, const int* in_sizes, int n_in,
                              void* d_out, int out_size, void* d_ws, size_t ws_size,
                              hipStream_t stream) {
  const float* H_Q        = (const float*)d_in[0];
  const float* H_C        = (const float*)d_in[1];
  const int*   eQC_src    = (const int*)d_in[2];
  const int*   eQC_dst    = (const int*)d_in[3];
  const int*   eCQ_src    = (const int*)d_in[4];
  const int*   eCQ_dst    = (const int*)d_in[5];
  const float* deg_QC_src = (const float*)d_in[6];
  const float* deg_QC_dst = (const float*)d_in[7];
  const float* deg_CQ_src = (const float*)d_in[8];
  const float* deg_CQ_dst = (const float*)d_in[9];
  const float* ln_g_Q     = (const float*)d_in[10];
  const float* ln_b_Q     = (const float*)d_in[11];
  const float* Wres_Q     = (const float*)d_in[12];
  const float* ln_g_C     = (const float*)d_in[13];
  const float* ln_b_C     = (const float*)d_in[14];
  const float* Wres_C     = (const float*)d_in[15];
  const float* Wrel_QC    = (const float*)d_in[16];
  const float* Wrel_CQ    = (const float*)d_in[17];
  const float* gate_QC    = (const float*)d_in[18];
  const float* gate_CQ    = (const float*)d_in[19];
  const float* W1_Q       = (const float*)d_in[20];
  const float* b1_Q       = (const float*)d_in[21];
  const float* W2_Q       = (const float*)d_in[22];
  const float* b2_Q       = (const float*)d_in[23];
  const float* W1_C       = (const float*)d_in[24];
  const float* b1_C       = (const float*)d_in[25];
  const float* W2_C       = (const float*)d_in[26];
  const float* b2_C       = (const float*)d_in[27];

  char* ws = (char*)d_ws;
  size_t o = 0;
  auto alloc = [&](size_t bytes) -> char* {
    char* p = ws + o;
    o += (bytes + 255) & ~(size_t)255;
    return p;
  };
  bf16* xnbQ = (bf16*)alloc((size_t)NQn * 128 * 2);
  bf16* xnbC = (bf16*)alloc((size_t)NCn * 128 * 2);
  int*  csrQC = (int*)alloc((size_t)En * 4);
  int*  csrCQ = (int*)alloc((size_t)En * 4);
  bf16* projQ = (bf16*)alloc((size_t)NQn * 128 * 2);
  bf16* projC = (bf16*)alloc((size_t)NCn * 128 * 2);
  bf16* msgQ  = (bf16*)alloc((size_t)NQn * 128 * 2);
  bf16* msgC  = (bf16*)alloc((size_t)NCn * 128 * 2);
  uint2* ebufQC = (uint2*)alloc((size_t)En * 8);
  uint2* ebufCQ = (uint2*)alloc((size_t)En * 8);
  bf16* WresQt = (bf16*)alloc(128 * 128 * 2);
  bf16* WresCt = (bf16*)alloc(128 * 128 * 2);
  bf16* WrelQCt = (bf16*)alloc(128 * 128 * 2);
  bf16* WrelCQt = (bf16*)alloc(128 * 128 * 2);
  bf16* W1Qt = (bf16*)alloc(256 * 256 * 2);
  bf16* W1Ct = (bf16*)alloc(256 * 256 * 2);
  bf16* W2Qt = (bf16*)alloc(128 * 256 * 2);
  bf16* W2Ct = (bf16*)alloc(128 * 256 * 2);
  int* bcnt   = (int*)alloc(1536 * 4);
  int* bbaseQC = (int*)alloc(513 * 4);
  int* bbaseCQ = (int*)alloc(1025 * 4);
  int* gcurQC = (int*)alloc(512 * 4);
  int* gcurCQ = (int*)alloc(1024 * 4);
  int* offsQC = (int*)alloc((size_t)NCn * 4);
  int* offsCQ = (int*)alloc((size_t)NQn * 4);

  float* outQ = (float*)d_out;
  float* outC = (float*)d_out + (size_t)NQn * 128;

  // 1. weight pack + bucket bases
  wtrans_all<<<dim3(256, 8), 256, 0, stream>>>(
      Wres_Q, WresQt, Wres_C, WresCt, Wrel_QC, WrelQCt, Wrel_CQ, WrelCQt,
      W1_Q, W1Qt, W1_C, W1Ct, W2_Q, W2Qt, W2_C, W2Ct);
  bucket_hist<<<384, 256, 0, stream>>>(deg_QC_dst, deg_CQ_dst, bcnt);
  bucket_scan<<<1, 1024, 0, stream>>>(bcnt, bbaseQC, gcurQC, bbaseCQ, gcurCQ);

  // 2. merged edge partition + merged CSR build
  bucketA2<<<512, 256, 0, stream>>>(eQC_src, eQC_dst, gcurQC, ebufQC, 256,
                                    eCQ_src, eCQ_dst, gcurCQ, ebufCQ);
  bucketB22<<<1536, 256, 0, stream>>>(ebufQC, bbaseQC, deg_QC_dst, offsQC,
                                      csrQC, 512,
                                      ebufCQ, bbaseCQ, deg_CQ_dst, offsCQ,
                                      csrCQ);

  // 3. merged fused proj+xn
  dual_gemm2<<<NQn / 64 + NCn / 64, 256, 0, stream>>>(
      H_Q, ln_g_Q, ln_b_Q, WresQt, WrelQCt, deg_QC_src, projQ, xnbQ, NQn / 64,
      H_C, ln_g_C, ln_b_C, WresCt, WrelCQt, deg_CQ_src, projC, xnbC);

  // 4. gathers, split by relation
  gather_one<<<NQn / 4, 256, 0, stream>>>(xnbC, csrCQ, offsCQ, deg_CQ_dst,
                                          gate_CQ, msgQ);
  gather_one<<<NCn / 4, 256, 0, stream>>>(xnbQ, csrQC, offsQC, deg_QC_dst,
                                          gate_QC, msgC);

  // 5. merged fused MLP (f32-out via LDS staging, vectorized residual)
  mlp_fused2<<<NQn / 64 + NCn / 64, 256, 0, stream>>>(
      projQ, msgQ, W1Qt, b1_Q, W2Qt, b2_Q, outQ, NQn / 64,
      projC, msgC, W1Ct, b1_C, W2Ct, b2_C, outC);
}

// Round 16
// 265.127 us; speedup vs baseline: 1.1645x; 1.1645x over previous
//
#include <hip/hip_runtime.h>
#include <stdint.h>

// Problem sizes (fixed by the reference)
#define NQn 131072
#define NCn 65536
#define En  1048576
// D = 128, HID = 256

typedef __bf16 bf16;
typedef __bf16 bf16x2 __attribute__((ext_vector_type(2)));
typedef __bf16 bf16x4 __attribute__((ext_vector_type(4)));
typedef __bf16 bf16x8 __attribute__((ext_vector_type(8)));
typedef float  f32x4  __attribute__((ext_vector_type(4)));

// ---------------------------------------------------------------------------
// Weight pack: fragment-major layout for MFMA B-operand (see R8 notes).
// ---------------------------------------------------------------------------
__global__ void wtrans_all(
    const float* __restrict__ w0, bf16* __restrict__ t0,
    const float* __restrict__ w1, bf16* __restrict__ t1,
    const float* __restrict__ w2, bf16* __restrict__ t2,
    const float* __restrict__ w3, bf16* __restrict__ t3,
    const float* __restrict__ w4, bf16* __restrict__ t4,
    const float* __restrict__ w5, bf16* __restrict__ t5,
    const float* __restrict__ w6, bf16* __restrict__ t6,
    const float* __restrict__ w7, bf16* __restrict__ t7) {
  const float* W; bf16* T; int K, M;
  switch (blockIdx.y) {
    case 0: W = w0; T = t0; K = 128; M = 128; break;  // Wres_Q
    case 1: W = w1; T = t1; K = 128; M = 128; break;  // Wres_C
    case 2: W = w2; T = t2; K = 128; M = 128; break;  // Wrel_QC
    case 3: W = w3; T = t3; K = 128; M = 128; break;  // Wrel_CQ
    case 4: W = w4; T = t4; K = 256; M = 256; break;  // W1_Q
    case 5: W = w5; T = t5; K = 256; M = 256; break;  // W1_C
    case 6: W = w6; T = t6; K = 256; M = 128; break;  // W2_Q
    default: W = w7; T = t7; K = 256; M = 128; break; // W2_C
  }
  int t = blockIdx.x * 256 + threadIdx.x;
  if (t >= K * M) return;
  int KB = K >> 5;
  int frag = t >> 9, within = t & 511;
  int lane = within >> 3, j = within & 7;
  int mb = frag / KB, kb = frag % KB;
  int m = mb * 16 + (lane & 15);
  int k = kb * 32 + (lane >> 4) * 8 + j;
  T[t] = (bf16)W[k * M + m];
}

// ---------------------------------------------------------------------------
// dual_tile: one 64-row tile: proj = LN(H)@Wres, xn = (H@Wrel)*deg^-1/2.
// Uses lds[0..32768). Epilogue staged through LDS -> bf16x8 coalesced stores.
// ---------------------------------------------------------------------------
__device__ __forceinline__ void dual_tile(
    unsigned char* lds, int bid,
    const float* __restrict__ H, const float* __restrict__ lng,
    const float* __restrict__ lnb, const bf16* __restrict__ Wres,
    const bf16* __restrict__ Wrel, const float* __restrict__ degsrc,
    bf16* __restrict__ proj, bf16* __restrict__ xn) {
  const int tid = threadIdx.x;
  const int row0 = bid * 64;
  const int wid = tid >> 6, lane = tid & 63;
  const int wrow = (wid >> 1) * 32, wcol = (wid & 1) * 64;

  #pragma unroll
  for (int it = 0; it < 8; ++it) {
    int lin = it * 256 + tid;
    int r = lin >> 5;
    int c = (lin & 31) * 4;
    float4 v = *(const float4*)(H + (size_t)(row0 + r) * 128 + c);
    float s = v.x + v.y + v.z + v.w;
    #pragma unroll
    for (int o = 16; o; o >>= 1) s += __shfl_xor(s, o, 64);
    float mean = s * (1.0f / 128.0f);
    float d0 = v.x - mean, d1 = v.y - mean, d2 = v.z - mean, d3 = v.w - mean;
    float q = d0 * d0 + d1 * d1 + d2 * d2 + d3 * d3;
    #pragma unroll
    for (int o = 16; o; o >>= 1) q += __shfl_xor(q, o, 64);
    float rsv = rsqrtf(q * (1.0f / 128.0f) + 1e-5f);
    float4 gg = *(const float4*)(lng + c);
    float4 bb = *(const float4*)(lnb + c);
    bf16x4 w;
    w[0] = (bf16)(d0 * rsv * gg.x + bb.x);
    w[1] = (bf16)(d1 * rsv * gg.y + bb.y);
    w[2] = (bf16)(d2 * rsv * gg.z + bb.z);
    w[3] = (bf16)(d3 * rsv * gg.w + bb.w);
    int off = r * 256 + ((c * 2) ^ ((r & 7) << 4));
    *(bf16x4*)(lds + off) = w;
    bf16x4 rw;
    rw[0] = (bf16)v.x; rw[1] = (bf16)v.y; rw[2] = (bf16)v.z; rw[3] = (bf16)v.w;
    *(bf16x4*)(lds + 16384 + off) = rw;
  }
  __syncthreads();

  const int rloc = wrow + (lane >> 4) * 4;
  const int cloc = wcol + (lane & 15);

  // pass 0: proj = lnh @ Wres
  {
    f32x4 acc[2][4] = {};
    #pragma unroll
    for (int kk = 0; kk < 4; ++kk) {
      const int kb = kk * 64 + (lane >> 4) * 16;
      bf16x8 af[2], bfv[4];
      #pragma unroll
      for (int fc = 0; fc < 4; ++fc) {
        int cblk = (wid & 1) * 4 + fc;
        bfv[fc] = *(const bf16x8*)(Wres + ((size_t)(cblk * 4 + kk) * 64 + lane) * 8);
      }
      #pragma unroll
      for (int fr = 0; fr < 2; ++fr) {
        int ar = wrow + fr * 16 + (lane & 15);
        af[fr] = *(const bf16x8*)(lds + ar * 256 + (kb ^ ((ar & 7) << 4)));
      }
      #pragma unroll
      for (int fr = 0; fr < 2; ++fr)
        #pragma unroll
        for (int fc = 0; fc < 4; ++fc)
          acc[fr][fc] = __builtin_amdgcn_mfma_f32_16x16x32_bf16(
              af[fr], bfv[fc], acc[fr][fc], 0, 0, 0);
    }
    __syncthreads();
    #pragma unroll
    for (int fr = 0; fr < 2; ++fr)
      #pragma unroll
      for (int fc = 0; fc < 4; ++fc)
        #pragma unroll
        for (int r = 0; r < 4; ++r) {
          int row = rloc + fr * 16 + r;
          int colb = (cloc + fc * 16) * 2;
          *(bf16*)(lds + row * 256 + (colb ^ ((row & 7) << 4))) =
              (bf16)acc[fr][fc][r];
        }
  }

  // pass 1: xn = (hb @ Wrel) * invsqrt(deg)
  {
    f32x4 acc[2][4] = {};
    #pragma unroll
    for (int kk = 0; kk < 4; ++kk) {
      const int kb = kk * 64 + (lane >> 4) * 16;
      bf16x8 af[2], bfv[4];
      #pragma unroll
      for (int fc = 0; fc < 4; ++fc) {
        int cblk = (wid & 1) * 4 + fc;
        bfv[fc] = *(const bf16x8*)(Wrel + ((size_t)(cblk * 4 + kk) * 64 + lane) * 8);
      }
      #pragma unroll
      for (int fr = 0; fr < 2; ++fr) {
        int ar = wrow + fr * 16 + (lane & 15);
        af[fr] = *(const bf16x8*)(lds + 16384 + ar * 256 + (kb ^ ((ar & 7) << 4)));
      }
      #pragma unroll
      for (int fr = 0; fr < 2; ++fr)
        #pragma unroll
        for (int fc = 0; fc < 4; ++fc)
          acc[fr][fc] = __builtin_amdgcn_mfma_f32_16x16x32_bf16(
              af[fr], bfv[fc], acc[fr][fc], 0, 0, 0);
    }
    __syncthreads();
    #pragma unroll
    for (int fr = 0; fr < 2; ++fr) {
      float rs[4];
      #pragma unroll
      for (int r = 0; r < 4; ++r) {
        float dv = degsrc[row0 + rloc + fr * 16 + r];
        rs[r] = dv > 0.f ? rsqrtf(dv) : 0.f;
      }
      #pragma unroll
      for (int fc = 0; fc < 4; ++fc)
        #pragma unroll
        for (int r = 0; r < 4; ++r) {
          int row = rloc + fr * 16 + r;
          int colb = (cloc + fc * 16) * 2;
          *(bf16*)(lds + 16384 + row * 256 + (colb ^ ((row & 7) << 4))) =
              (bf16)(acc[fr][fc][r] * rs[r]);
        }
    }
  }
  __syncthreads();

  #pragma unroll
  for (int it = 0; it < 8; ++it) {
    int lin = it * 256 + tid;
    int pb = (lin < 1024) ? 0 : 16384;
    bf16* dst = (lin < 1024) ? proj : xn;
    int chunk = lin & 1023;
    int r = chunk >> 4;
    int cb = (chunk & 15) * 16;
    bf16x8 v = *(const bf16x8*)(lds + pb + r * 256 + (cb ^ ((r & 7) << 4)));
    *(bf16x8*)((char*)(dst + (size_t)(row0 + r) * 128) + cb) = v;
  }
}

// ---------------------------------------------------------------------------
// bucketA_chunk: partition one 2048-edge chunk into bucket-grouped ebuf
// (bucket = dst>>7). Uses the 33792B lds union.
// ---------------------------------------------------------------------------
__device__ __forceinline__ void bucketA_chunk(
    unsigned char* ldsraw, int chunk,
    const int* __restrict__ esrc, const int* __restrict__ edst,
    int* __restrict__ gcur, uint2* __restrict__ ebuf, int nb) {
  int* lcount = (int*)ldsraw;
  int* lexcl  = (int*)(ldsraw + 4096);
  int* lbase  = (int*)(ldsraw + 8192);
  int* lofs   = (int*)(ldsraw + 12288);
  int* ss     = (int*)(ldsraw + 16384);
  uint2* stage = (uint2*)(ldsraw + 17408);
  const int t = threadIdx.x;
  for (int b = t; b < 1024; b += 256) lcount[b] = 0;
  __syncthreads();
  const int e0 = chunk * 2048;
  uint2 ed[8];
  #pragma unroll
  for (int j = 0; j < 8; ++j) {
    int e = e0 + j * 256 + t;
    ed[j].x = (unsigned)esrc[e];
    ed[j].y = (unsigned)edst[e];
    atomicAdd(&lcount[ed[j].y >> 7], 1);
  }
  __syncthreads();
  int c[4]; int mysum = 0;
  #pragma unroll
  for (int j = 0; j < 4; ++j) { c[j] = lcount[t * 4 + j]; mysum += c[j]; }
  ss[t] = mysum;
  __syncthreads();
  for (int o = 1; o < 256; o <<= 1) {
    int x = (t >= o) ? ss[t - o] : 0;
    __syncthreads();
    ss[t] += x;
    __syncthreads();
  }
  int run = ss[t] - mysum;
  #pragma unroll
  for (int j = 0; j < 4; ++j) { lexcl[t * 4 + j] = run; run += c[j]; }
  __syncthreads();
  for (int b = t; b < 1024; b += 256) {
    lbase[b] = (b < nb && lcount[b]) ? atomicAdd(&gcur[b], lcount[b]) : 0;
    lofs[b]  = lexcl[b];
  }
  __syncthreads();
  #pragma unroll
  for (int j = 0; j < 8; ++j) {
    int b = ed[j].y >> 7;
    int p = atomicAdd(&lofs[b], 1);
    stage[p] = ed[j];
  }
  __syncthreads();
  for (int i = t; i < 2048; i += 256) {
    uint2 v = stage[i];
    int b = v.y >> 7;
    ebuf[lbase[b] + (i - lexcl[b])] = v;
  }
}

// ---------------------------------------------------------------------------
// fusedA: dual_gemm (Q:2048, C:1024 tiles) || bucketA (QC:512, CQ:512 chunks).
// Both halves are linear-streaming (no random-granule pollution — R11's
// failure was gather||mlp, not this pair).
// ---------------------------------------------------------------------------
__global__ __launch_bounds__(256, 4) void fusedA(
    const float* __restrict__ HQ, const float* __restrict__ lngQ,
    const float* __restrict__ lnbQ, const bf16* __restrict__ WresQ,
    const bf16* __restrict__ WrelQ, const float* __restrict__ degQ,
    bf16* __restrict__ projQ, bf16* __restrict__ xnQ,
    const float* __restrict__ HC, const float* __restrict__ lngC,
    const float* __restrict__ lnbC, const bf16* __restrict__ WresC,
    const bf16* __restrict__ WrelC, const float* __restrict__ degC,
    bf16* __restrict__ projC, bf16* __restrict__ xnC,
    const int* __restrict__ eQCs, const int* __restrict__ eQCd,
    int* __restrict__ gcurQC, uint2* __restrict__ ebufQC,
    const int* __restrict__ eCQs, const int* __restrict__ eCQd,
    int* __restrict__ gcurCQ, uint2* __restrict__ ebufCQ) {
  __shared__ __align__(16) unsigned char lds[33792];
  int bid = blockIdx.x;
  if (bid < 2048) {
    dual_tile(lds, bid, HQ, lngQ, lnbQ, WresQ, WrelQ, degQ, projQ, xnQ);
  } else if (bid < 3072) {
    dual_tile(lds, bid - 2048, HC, lngC, lnbC, WresC, WrelC, degC, projC, xnC);
  } else if (bid < 3584) {
    bucketA_chunk(lds, bid - 3072, eQCs, eQCd, gcurQC, ebufQC, 512);
  } else {
    bucketA_chunk(lds, bid - 3584, eCQs, eCQd, gcurCQ, ebufCQ, 1024);
  }
}

// ---------------------------------------------------------------------------
// mlp_fused2 (R14-exact, measured 80us): out = proj + GELU([proj|msg]@W1+b1)
// @W2 + b2. 64-row tile, 4 waves, 32KB LDS, (256,4) (=(256,5) spills, R13).
// Residual from global (LDS variant +15us, R12); direct scalar f32 stores
// (LDS-staged f32-out spilled, R15). Swizzle (r&7): 2-way conflicts free.
// ---------------------------------------------------------------------------
__global__ __launch_bounds__(256, 4) void mlp_fused2(
    const bf16* __restrict__ projQ, const bf16* __restrict__ msgQ,
    const bf16* __restrict__ W1Q, const float* __restrict__ b1Q,
    const bf16* __restrict__ W2Q, const float* __restrict__ b2Q,
    float* __restrict__ outQ, int splitQ,
    const bf16* __restrict__ projC, const bf16* __restrict__ msgC,
    const bf16* __restrict__ W1C, const float* __restrict__ b1C,
    const bf16* __restrict__ W2C, const float* __restrict__ b2C,
    float* __restrict__ outC) {
  __shared__ __align__(16) unsigned char lds[32768];
  const bf16 *proj, *msg, *W1p, *W2p;
  const float *b1, *b2;
  float* out;
  int bid = blockIdx.x;
  if (bid < splitQ) {
    proj = projQ; msg = msgQ; W1p = W1Q; b1 = b1Q; W2p = W2Q; b2 = b2Q; out = outQ;
  } else {
    bid -= splitQ;
    proj = projC; msg = msgC; W1p = W1C; b1 = b1C; W2p = W2C; b2 = b2C; out = outC;
  }
  const int tid = threadIdx.x;
  const int row0 = bid * 64;
  const int wid = tid >> 6, lane = tid & 63;

  // stage A = [proj | msg], 64 rows x 512B
  #pragma unroll
  for (int it = 0; it < 8; ++it) {
    int lin = it * 256 + tid;
    int r = lin >> 5;
    int cb = (lin & 31) * 16;
    const bf16* src = (cb < 256) ? (proj + (size_t)(row0 + r) * 128)
                                 : (msg + (size_t)(row0 + r) * 128 - 128);
    bf16x8 v = *(const bf16x8*)((const char*)src + cb);
    *(bf16x8*)(lds + r * 512 + (cb ^ ((r & 7) << 4))) = v;
  }
  __syncthreads();

  // phase 1: h[64][256] = A @ W1 (K=256); wave w covers cols w*64..+63
  f32x4 acc1[4][4] = {};
  #pragma unroll
  for (int kk = 0; kk < 8; ++kk) {
    const int kb = kk * 64 + (lane >> 4) * 16;
    bf16x8 af[4], bfv[4];
    #pragma unroll
    for (int fc = 0; fc < 4; ++fc) {
      int cblk = wid * 4 + fc;
      bfv[fc] = *(const bf16x8*)(W1p + ((size_t)(cblk * 8 + kk) * 64 + lane) * 8);
    }
    #pragma unroll
    for (int fr = 0; fr < 4; ++fr) {
      int ar = fr * 16 + (lane & 15);
      af[fr] = *(const bf16x8*)(lds + ar * 512 + (kb ^ ((ar & 7) << 4)));
    }
    #pragma unroll
    for (int fr = 0; fr < 4; ++fr)
      #pragma unroll
      for (int fc = 0; fc < 4; ++fc)
        acc1[fr][fc] = __builtin_amdgcn_mfma_f32_16x16x32_bf16(
            af[fr], bfv[fc], acc1[fr][fc], 0, 0, 0);
  }
  __syncthreads();   // all A reads done -> safe to overwrite with h

  // GELU + b1 -> h panel (64 rows x 512B, same swizzle)
  {
    const int rb = (lane >> 4) * 4;
    const int cb0 = wid * 64 + (lane & 15);
    #pragma unroll
    for (int fc = 0; fc < 4; ++fc) {
      int col = cb0 + fc * 16;
      float bv = b1[col];
      #pragma unroll
      for (int fr = 0; fr < 4; ++fr) {
        #pragma unroll
        for (int r = 0; r < 4; ++r) {
          int row = rb + fr * 16 + r;
          float x = acc1[fr][fc][r] + bv;
          float u2 = 1.5957691216057308f * (x + 0.044715f * x * x * x);
          float e = __expf(u2);
          x = 0.5f * x * (1.f + (1.f - 2.f / (e + 1.f)));
          *(bf16*)(lds + row * 512 + ((col * 2) ^ ((row & 7) << 4))) = (bf16)x;
        }
      }
    }
  }
  __syncthreads();

  // phase 2: out = proj + h @ W2 + b2; wave grid 2x2 (32x64)
  const int wrow2 = (wid >> 1) * 32;
  const int wcol2 = (wid & 1) * 64;
  f32x4 acc2[2][4] = {};
  #pragma unroll
  for (int kk = 0; kk < 8; ++kk) {
    const int kb = kk * 64 + (lane >> 4) * 16;
    bf16x8 af[2], bfv[4];
    #pragma unroll
    for (int fc = 0; fc < 4; ++fc) {
      int cblk = (wid & 1) * 4 + fc;
      bfv[fc] = *(const bf16x8*)(W2p + ((size_t)(cblk * 8 + kk) * 64 + lane) * 8);
    }
    #pragma unroll
    for (int fr = 0; fr < 2; ++fr) {
      int ar = wrow2 + fr * 16 + (lane & 15);
      af[fr] = *(const bf16x8*)(lds + ar * 512 + (kb ^ ((ar & 7) << 4)));
    }
    #pragma unroll
    for (int fr = 0; fr < 2; ++fr)
      #pragma unroll
      for (int fc = 0; fc < 4; ++fc)
        acc2[fr][fc] = __builtin_amdgcn_mfma_f32_16x16x32_bf16(
            af[fr], bfv[fc], acc2[fr][fc], 0, 0, 0);
  }
  const int rbase = wrow2 + (lane >> 4) * 4;
  const int cbase = wcol2 + (lane & 15);
  #pragma unroll
  for (int fr = 0; fr < 2; ++fr) {
    #pragma unroll
    for (int fc = 0; fc < 4; ++fc) {
      int col = cbase + fc * 16;
      float bv = b2[col];
      #pragma unroll
      for (int r = 0; r < 4; ++r) {
        int row = row0 + rbase + fr * 16 + r;
        out[(size_t)row * 128 + col] =
            acc2[fr][fc][r] + bv + (float)proj[(size_t)row * 128 + col];
      }
    }
  }
}

// ---------------------------------------------------------------------------
// Bucket histogram + scan (bucket = 128 dst rows). bcnt: [512 QC][1024 CQ]
// ---------------------------------------------------------------------------
__global__ __launch_bounds__(256) void bucket_hist(
    const float* __restrict__ degQC, const float* __restrict__ degCQ,
    int* __restrict__ bcnt) {
  int w = (blockIdx.x * 256 + threadIdx.x) >> 6;
  int lane = threadIdx.x & 63;
  const float* deg = (w < 512) ? (degQC + (size_t)w * 128)
                               : (degCQ + (size_t)(w - 512) * 128);
  float s = deg[lane] + deg[lane + 64];
  #pragma unroll
  for (int o = 32; o; o >>= 1) s += __shfl_xor(s, o, 64);
  if (lane == 0) bcnt[w] = (int)(s + 0.5f);
}

__global__ __launch_bounds__(1024) void bucket_scan(
    const int* __restrict__ bcnt,
    int* __restrict__ baseQC, int* __restrict__ gcurQC,
    int* __restrict__ baseCQ, int* __restrict__ gcurCQ) {
  __shared__ int ss[1024];
  const int t = threadIdx.x;
  int v = (t < 512) ? bcnt[t] : 0;
  ss[t] = v;
  __syncthreads();
  for (int o = 1; o < 1024; o <<= 1) {
    int x = (t >= o) ? ss[t - o] : 0;
    __syncthreads();
    ss[t] += x;
    __syncthreads();
  }
  if (t < 512) { int e = ss[t] - v; baseQC[t] = e; gcurQC[t] = e; }
  if (t == 0) baseQC[512] = En;
  __syncthreads();
  int v2 = bcnt[512 + t];
  ss[t] = v2;
  __syncthreads();
  for (int o = 1; o < 1024; o <<= 1) {
    int x = (t >= o) ? ss[t - o] : 0;
    __syncthreads();
    ss[t] += x;
    __syncthreads();
  }
  { int e = ss[t] - v2; baseCQ[t] = e; gcurCQ[t] = e; }
  if (t == 0) baseCQ[1024] = En;
}

// ---------------------------------------------------------------------------
// bucketB22: merged Q+C. Per-bucket deg-scan -> offs; fill csr via INT LDS
// atomics (csr window contiguous, L2-hot).
// ---------------------------------------------------------------------------
__global__ __launch_bounds__(256) void bucketB22(
    const uint2* __restrict__ ebufQ, const int* __restrict__ bbaseQ,
    const float* __restrict__ degQ, int* __restrict__ offsQ,
    int* __restrict__ csrQ, int splitQ,
    const uint2* __restrict__ ebufC, const int* __restrict__ bbaseC,
    const float* __restrict__ degC, int* __restrict__ offsC,
    int* __restrict__ csrC) {
  __shared__ int sdeg[128];
  __shared__ int lcur[128];
  const uint2* ebuf; const int* bbase; const float* degdst; int* offs; int* csr;
  int b = blockIdx.x;
  if (b < splitQ) { ebuf = ebufQ; bbase = bbaseQ; degdst = degQ; offs = offsQ; csr = csrQ; }
  else { b -= splitQ; ebuf = ebufC; bbase = bbaseC; degdst = degC; offs = offsC; csr = csrC; }
  const int t = threadIdx.x;
  const int base = bbase[b], end = bbase[b + 1];
  int myv = 0;
  if (t < 128) {
    myv = (int)(degdst[(size_t)b * 128 + t] + 0.5f);
    sdeg[t] = myv;
  }
  __syncthreads();
  for (int o = 1; o < 128; o <<= 1) {
    int x = (t < 128 && t >= o) ? sdeg[t - o] : 0;
    __syncthreads();
    if (t < 128) sdeg[t] += x;
    __syncthreads();
  }
  if (t < 128) {
    int excl = sdeg[t] - myv;
    lcur[t] = excl;
    offs[(size_t)b * 128 + t] = base + excl;
  }
  __syncthreads();
  for (int i = base + t; i < end; i += 256) {
    uint2 v = ebuf[i];
    int p = atomicAdd(&lcur[v.y & 127], 1);
    csr[base + p] = (int)v.x;
  }
}

// ---------------------------------------------------------------------------
// gather_one: one relation. One wave per dst row, half-wave pairing,
// 8 edges in flight.
// ---------------------------------------------------------------------------
__global__ __launch_bounds__(256) void gather_one(
    const bf16* __restrict__ Xn, const int* __restrict__ csr,
    const int* __restrict__ offs, const float* __restrict__ degdst,
    const float* __restrict__ gate, bf16* __restrict__ msg) {
  int d = blockIdx.x * 4 + (threadIdx.x >> 6);
  int lane = threadIdx.x & 63;
  int half = lane >> 5, sl = lane & 31;
  float dv = degdst[d];
  int cnt = (int)(dv + 0.5f);
  int start = offs[d];
  float a0 = 0.f, a1 = 0.f, a2 = 0.f, a3 = 0.f;
  int i = 0;
  for (; i + 8 <= cnt; i += 8) {
    int s0 = csr[start + i + half * 4 + 0];
    int s1 = csr[start + i + half * 4 + 1];
    int s2 = csr[start + i + half * 4 + 2];
    int s3 = csr[start + i + half * 4 + 3];
    bf16x4 v0 = *(const bf16x4*)(Xn + (size_t)s0 * 128 + sl * 4);
    bf16x4 v1 = *(const bf16x4*)(Xn + (size_t)s1 * 128 + sl * 4);
    bf16x4 v2 = *(const bf16x4*)(Xn + (size_t)s2 * 128 + sl * 4);
    bf16x4 v3 = *(const bf16x4*)(Xn + (size_t)s3 * 128 + sl * 4);
    a0 += (float)v0[0] + (float)v1[0] + (float)v2[0] + (float)v3[0];
    a1 += (float)v0[1] + (float)v1[1] + (float)v2[1] + (float)v3[1];
    a2 += (float)v0[2] + (float)v1[2] + (float)v2[2] + (float)v3[2];
    a3 += (float)v0[3] + (float)v1[3] + (float)v2[3] + (float)v3[3];
  }
  for (; i + 2 <= cnt; i += 2) {
    int s0 = csr[start + i + half];
    bf16x4 v0 = *(const bf16x4*)(Xn + (size_t)s0 * 128 + sl * 4);
    a0 += (float)v0[0]; a1 += (float)v0[1];
    a2 += (float)v0[2]; a3 += (float)v0[3];
  }
  if (i < cnt && half == 0) {
    int s0 = csr[start + i];
    bf16x4 v0 = *(const bf16x4*)(Xn + (size_t)s0 * 128 + sl * 4);
    a0 += (float)v0[0]; a1 += (float)v0[1];
    a2 += (float)v0[2]; a3 += (float)v0[3];
  }
  a0 += __shfl_xor(a0, 32, 64);
  a1 += __shfl_xor(a1, 32, 64);
  a2 += __shfl_xor(a2, 32, 64);
  a3 += __shfl_xor(a3, 32, 64);
  if (half == 0) {
    float sc = (dv > 0.f ? rsqrtf(dv) : 0.f) * gate[0];
    bf16x4 r;
    r[0] = (bf16)(a0 * sc); r[1] = (bf16)(a1 * sc);
    r[2] = (bf16)(a2 * sc); r[3] = (bf16)(a3 * sc);
    *(bf16x4*)(msg + (size_t)d * 128 + sl * 4) = r;
  }
}

// ---------------------------------------------------------------------------
extern "C" void kernel_launch(void* const* d_in, const int* in_sizes, int n_in,
                              void* d_out, int out_size, void* d_ws, size_t ws_size,
                              hipStream_t stream) {
  const float* H_Q        = (const float*)d_in[0];
  const float* H_C        = (const float*)d_in[1];
  const int*   eQC_src    = (const int*)d_in[2];
  const int*   eQC_dst    = (const int*)d_in[3];
  const int*   eCQ_src    = (const int*)d_in[4];
  const int*   eCQ_dst    = (const int*)d_in[5];
  const float* deg_QC_src = (const float*)d_in[6];
  const float* deg_QC_dst = (const float*)d_in[7];
  const float* deg_CQ_src = (const float*)d_in[8];
  const float* deg_CQ_dst = (const float*)d_in[9];
  const float* ln_g_Q     = (const float*)d_in[10];
  const float* ln_b_Q     = (const float*)d_in[11];
  const float* Wres_Q     = (const float*)d_in[12];
  const float* ln_g_C     = (const float*)d_in[13];
  const float* ln_b_C     = (const float*)d_in[14];
  const float* Wres_C     = (const float*)d_in[15];
  const float* Wrel_QC    = (const float*)d_in[16];
  const float* Wrel_CQ    = (const float*)d_in[17];
  const float* gate_QC    = (const float*)d_in[18];
  const float* gate_CQ    = (const float*)d_in[19];
  const float* W1_Q       = (const float*)d_in[20];
  const float* b1_Q       = (const float*)d_in[21];
  const float* W2_Q       = (const float*)d_in[22];
  const float* b2_Q       = (const float*)d_in[23];
  const float* W1_C       = (const float*)d_in[24];
  const float* b1_C       = (const float*)d_in[25];
  const float* W2_C       = (const float*)d_in[26];
  const float* b2_C       = (const float*)d_in[27];

  char* ws = (char*)d_ws;
  size_t o = 0;
  auto alloc = [&](size_t bytes) -> char* {
    char* p = ws + o;
    o += (bytes + 255) & ~(size_t)255;
    return p;
  };
  bf16* xnbQ = (bf16*)alloc((size_t)NQn * 128 * 2);
  bf16* xnbC = (bf16*)alloc((size_t)NCn * 128 * 2);
  int*  csrQC = (int*)alloc((size_t)En * 4);
  int*  csrCQ = (int*)alloc((size_t)En * 4);
  bf16* projQ = (bf16*)alloc((size_t)NQn * 128 * 2);
  bf16* projC = (bf16*)alloc((size_t)NCn * 128 * 2);
  bf16* msgQ  = (bf16*)alloc((size_t)NQn * 128 * 2);
  bf16* msgC  = (bf16*)alloc((size_t)NCn * 128 * 2);
  uint2* ebufQC = (uint2*)alloc((size_t)En * 8);
  uint2* ebufCQ = (uint2*)alloc((size_t)En * 8);
  bf16* WresQt = (bf16*)alloc(128 * 128 * 2);
  bf16* WresCt = (bf16*)alloc(128 * 128 * 2);
  bf16* WrelQCt = (bf16*)alloc(128 * 128 * 2);
  bf16* WrelCQt = (bf16*)alloc(128 * 128 * 2);
  bf16* W1Qt = (bf16*)alloc(256 * 256 * 2);
  bf16* W1Ct = (bf16*)alloc(256 * 256 * 2);
  bf16* W2Qt = (bf16*)alloc(128 * 256 * 2);
  bf16* W2Ct = (bf16*)alloc(128 * 256 * 2);
  int* bcnt   = (int*)alloc(1536 * 4);
  int* bbaseQC = (int*)alloc(513 * 4);
  int* bbaseCQ = (int*)alloc(1025 * 4);
  int* gcurQC = (int*)alloc(512 * 4);
  int* gcurCQ = (int*)alloc(1024 * 4);
  int* offsQC = (int*)alloc((size_t)NCn * 4);
  int* offsCQ = (int*)alloc((size_t)NQn * 4);

  float* outQ = (float*)d_out;
  float* outC = (float*)d_out + (size_t)NQn * 128;

  // 1. weight pack + bucket bases
  wtrans_all<<<dim3(256, 8), 256, 0, stream>>>(
      Wres_Q, WresQt, Wres_C, WresCt, Wrel_QC, WrelQCt, Wrel_CQ, WrelCQt,
      W1_Q, W1Qt, W1_C, W1Ct, W2_Q, W2Qt, W2_C, W2Ct);
  bucket_hist<<<384, 256, 0, stream>>>(deg_QC_dst, deg_CQ_dst, bcnt);
  bucket_scan<<<1, 1024, 0, stream>>>(bcnt, bbaseQC, gcurQC, bbaseCQ, gcurCQ);

  // 2. fusedA: dual_gemm (Q+C) || bucketA (QC+CQ) — both linear-streaming
  fusedA<<<4096, 256, 0, stream>>>(
      H_Q, ln_g_Q, ln_b_Q, WresQt, WrelQCt, deg_QC_src, projQ, xnbQ,
      H_C, ln_g_C, ln_b_C, WresCt, WrelCQt, deg_CQ_src, projC, xnbC,
      eQC_src, eQC_dst, gcurQC, ebufQC,
      eCQ_src, eCQ_dst, gcurCQ, ebufCQ);

  // 3. merged CSR build
  bucketB22<<<1536, 256, 0, stream>>>(ebufQC, bbaseQC, deg_QC_dst, offsQC,
                                      csrQC, 512,
                                      ebufCQ, bbaseCQ, deg_CQ_dst, offsCQ,
                                      csrCQ);

  // 4. gathers, split by relation
  gather_one<<<NQn / 4, 256, 0, stream>>>(xnbC, csrCQ, offsCQ, deg_CQ_dst,
                                          gate_CQ, msgQ);
  gather_one<<<NCn / 4, 256, 0, stream>>>(xnbQ, csrQC, offsQC, deg_QC_dst,
                                          gate_QC, msgC);

  // 5. merged fused MLP (R14-exact)
  mlp_fused2<<<NQn / 64 + NCn / 64, 256, 0, stream>>>(
      projQ, msgQ, W1Qt, b1_Q, W2Qt, b2_Q, outQ, NQn / 64,
      projC, msgC, W1Ct, b1_C, W2Ct, b2_C, outC);
}

// Round 17
// 263.072 us; speedup vs baseline: 1.1736x; 1.0078x over previous
//
#include <hip/hip_runtime.h>
#include <stdint.h>

// Problem sizes (fixed by the reference)
#define NQn 131072
#define NCn 65536
#define En  1048576
// D = 128, HID = 256

typedef __bf16 bf16;
typedef __bf16 bf16x2 __attribute__((ext_vector_type(2)));
typedef __bf16 bf16x4 __attribute__((ext_vector_type(4)));
typedef __bf16 bf16x8 __attribute__((ext_vector_type(8)));
typedef float  f32x4  __attribute__((ext_vector_type(4)));

// ---------------------------------------------------------------------------
// prep_kernel: weight fragment-pack (blocks 0..2047) + bucket histogram
// (blocks 2048..2431). Independent work merged into one dispatch.
// ---------------------------------------------------------------------------
__global__ __launch_bounds__(256) void prep_kernel(
    const float* __restrict__ w0, bf16* __restrict__ t0,
    const float* __restrict__ w1, bf16* __restrict__ t1,
    const float* __restrict__ w2, bf16* __restrict__ t2,
    const float* __restrict__ w3, bf16* __restrict__ t3,
    const float* __restrict__ w4, bf16* __restrict__ t4,
    const float* __restrict__ w5, bf16* __restrict__ t5,
    const float* __restrict__ w6, bf16* __restrict__ t6,
    const float* __restrict__ w7, bf16* __restrict__ t7,
    const float* __restrict__ degQC, const float* __restrict__ degCQ,
    int* __restrict__ bcnt) {
  int blk = blockIdx.x;
  if (blk >= 2048) {
    // bucket_hist: one wave per 128-dst bucket
    int w = ((blk - 2048) * 256 + threadIdx.x) >> 6;
    int lane = threadIdx.x & 63;
    const float* deg = (w < 512) ? (degQC + (size_t)w * 128)
                                 : (degCQ + (size_t)(w - 512) * 128);
    float s = deg[lane] + deg[lane + 64];
    #pragma unroll
    for (int o = 32; o; o >>= 1) s += __shfl_xor(s, o, 64);
    if (lane == 0) bcnt[w] = (int)(s + 0.5f);
    return;
  }
  // wtrans: 8 weights, 256 blocks each
  int wsel = blk >> 8;
  const float* W; bf16* T; int K, M;
  switch (wsel) {
    case 0: W = w0; T = t0; K = 128; M = 128; break;  // Wres_Q
    case 1: W = w1; T = t1; K = 128; M = 128; break;  // Wres_C
    case 2: W = w2; T = t2; K = 128; M = 128; break;  // Wrel_QC
    case 3: W = w3; T = t3; K = 128; M = 128; break;  // Wrel_CQ
    case 4: W = w4; T = t4; K = 256; M = 256; break;  // W1_Q
    case 5: W = w5; T = t5; K = 256; M = 256; break;  // W1_C
    case 6: W = w6; T = t6; K = 256; M = 128; break;  // W2_Q
    default: W = w7; T = t7; K = 256; M = 128; break; // W2_C
  }
  int t = (blk & 255) * 256 + threadIdx.x;
  if (t >= K * M) return;
  int KB = K >> 5;
  int frag = t >> 9, within = t & 511;
  int lane = within >> 3, j = within & 7;
  int mb = frag / KB, kb = frag % KB;
  int m = mb * 16 + (lane & 15);
  int k = kb * 32 + (lane >> 4) * 8 + j;
  T[t] = (bf16)W[k * M + m];
}

// ---------------------------------------------------------------------------
// dual_tile: one 64-row tile: proj = LN(H)@Wres, xn = (H@Wrel)*deg^-1/2.
// Uses lds[0..32768). Epilogue staged through LDS -> bf16x8 coalesced stores.
// ---------------------------------------------------------------------------
__device__ __forceinline__ void dual_tile(
    unsigned char* lds, int bid,
    const float* __restrict__ H, const float* __restrict__ lng,
    const float* __restrict__ lnb, const bf16* __restrict__ Wres,
    const bf16* __restrict__ Wrel, const float* __restrict__ degsrc,
    bf16* __restrict__ proj, bf16* __restrict__ xn) {
  const int tid = threadIdx.x;
  const int row0 = bid * 64;
  const int wid = tid >> 6, lane = tid & 63;
  const int wrow = (wid >> 1) * 32, wcol = (wid & 1) * 64;

  #pragma unroll
  for (int it = 0; it < 8; ++it) {
    int lin = it * 256 + tid;
    int r = lin >> 5;
    int c = (lin & 31) * 4;
    float4 v = *(const float4*)(H + (size_t)(row0 + r) * 128 + c);
    float s = v.x + v.y + v.z + v.w;
    #pragma unroll
    for (int o = 16; o; o >>= 1) s += __shfl_xor(s, o, 64);
    float mean = s * (1.0f / 128.0f);
    float d0 = v.x - mean, d1 = v.y - mean, d2 = v.z - mean, d3 = v.w - mean;
    float q = d0 * d0 + d1 * d1 + d2 * d2 + d3 * d3;
    #pragma unroll
    for (int o = 16; o; o >>= 1) q += __shfl_xor(q, o, 64);
    float rsv = rsqrtf(q * (1.0f / 128.0f) + 1e-5f);
    float4 gg = *(const float4*)(lng + c);
    float4 bb = *(const float4*)(lnb + c);
    bf16x4 w;
    w[0] = (bf16)(d0 * rsv * gg.x + bb.x);
    w[1] = (bf16)(d1 * rsv * gg.y + bb.y);
    w[2] = (bf16)(d2 * rsv * gg.z + bb.z);
    w[3] = (bf16)(d3 * rsv * gg.w + bb.w);
    int off = r * 256 + ((c * 2) ^ ((r & 7) << 4));
    *(bf16x4*)(lds + off) = w;
    bf16x4 rw;
    rw[0] = (bf16)v.x; rw[1] = (bf16)v.y; rw[2] = (bf16)v.z; rw[3] = (bf16)v.w;
    *(bf16x4*)(lds + 16384 + off) = rw;
  }
  __syncthreads();

  const int rloc = wrow + (lane >> 4) * 4;
  const int cloc = wcol + (lane & 15);

  // pass 0: proj = lnh @ Wres
  {
    f32x4 acc[2][4] = {};
    #pragma unroll
    for (int kk = 0; kk < 4; ++kk) {
      const int kb = kk * 64 + (lane >> 4) * 16;
      bf16x8 af[2], bfv[4];
      #pragma unroll
      for (int fc = 0; fc < 4; ++fc) {
        int cblk = (wid & 1) * 4 + fc;
        bfv[fc] = *(const bf16x8*)(Wres + ((size_t)(cblk * 4 + kk) * 64 + lane) * 8);
      }
      #pragma unroll
      for (int fr = 0; fr < 2; ++fr) {
        int ar = wrow + fr * 16 + (lane & 15);
        af[fr] = *(const bf16x8*)(lds + ar * 256 + (kb ^ ((ar & 7) << 4)));
      }
      #pragma unroll
      for (int fr = 0; fr < 2; ++fr)
        #pragma unroll
        for (int fc = 0; fc < 4; ++fc)
          acc[fr][fc] = __builtin_amdgcn_mfma_f32_16x16x32_bf16(
              af[fr], bfv[fc], acc[fr][fc], 0, 0, 0);
    }
    __syncthreads();
    #pragma unroll
    for (int fr = 0; fr < 2; ++fr)
      #pragma unroll
      for (int fc = 0; fc < 4; ++fc)
        #pragma unroll
        for (int r = 0; r < 4; ++r) {
          int row = rloc + fr * 16 + r;
          int colb = (cloc + fc * 16) * 2;
          *(bf16*)(lds + row * 256 + (colb ^ ((row & 7) << 4))) =
              (bf16)acc[fr][fc][r];
        }
  }

  // pass 1: xn = (hb @ Wrel) * invsqrt(deg)
  {
    f32x4 acc[2][4] = {};
    #pragma unroll
    for (int kk = 0; kk < 4; ++kk) {
      const int kb = kk * 64 + (lane >> 4) * 16;
      bf16x8 af[2], bfv[4];
      #pragma unroll
      for (int fc = 0; fc < 4; ++fc) {
        int cblk = (wid & 1) * 4 + fc;
        bfv[fc] = *(const bf16x8*)(Wrel + ((size_t)(cblk * 4 + kk) * 64 + lane) * 8);
      }
      #pragma unroll
      for (int fr = 0; fr < 2; ++fr) {
        int ar = wrow + fr * 16 + (lane & 15);
        af[fr] = *(const bf16x8*)(lds + 16384 + ar * 256 + (kb ^ ((ar & 7) << 4)));
      }
      #pragma unroll
      for (int fr = 0; fr < 2; ++fr)
        #pragma unroll
        for (int fc = 0; fc < 4; ++fc)
          acc[fr][fc] = __builtin_amdgcn_mfma_f32_16x16x32_bf16(
              af[fr], bfv[fc], acc[fr][fc], 0, 0, 0);
    }
    __syncthreads();
    #pragma unroll
    for (int fr = 0; fr < 2; ++fr) {
      float rs[4];
      #pragma unroll
      for (int r = 0; r < 4; ++r) {
        float dv = degsrc[row0 + rloc + fr * 16 + r];
        rs[r] = dv > 0.f ? rsqrtf(dv) : 0.f;
      }
      #pragma unroll
      for (int fc = 0; fc < 4; ++fc)
        #pragma unroll
        for (int r = 0; r < 4; ++r) {
          int row = rloc + fr * 16 + r;
          int colb = (cloc + fc * 16) * 2;
          *(bf16*)(lds + 16384 + row * 256 + (colb ^ ((row & 7) << 4))) =
              (bf16)(acc[fr][fc][r] * rs[r]);
        }
    }
  }
  __syncthreads();

  #pragma unroll
  for (int it = 0; it < 8; ++it) {
    int lin = it * 256 + tid;
    int pb = (lin < 1024) ? 0 : 16384;
    bf16* dst = (lin < 1024) ? proj : xn;
    int chunk = lin & 1023;
    int r = chunk >> 4;
    int cb = (chunk & 15) * 16;
    bf16x8 v = *(const bf16x8*)(lds + pb + r * 256 + (cb ^ ((r & 7) << 4)));
    *(bf16x8*)((char*)(dst + (size_t)(row0 + r) * 128) + cb) = v;
  }
}

// ---------------------------------------------------------------------------
// bucketA_chunk: partition one 2048-edge chunk into bucket-grouped ebuf
// (bucket = dst>>7). LDS budget 29696B (lofs aliases lcount — safe: each
// bucket b is read-then-written by exactly one thread in the init loop).
// Keeps the fusedA union at exactly 32768B -> 5 blocks/CU.
// ---------------------------------------------------------------------------
__device__ __forceinline__ void bucketA_chunk(
    unsigned char* ldsraw, int chunk,
    const int* __restrict__ esrc, const int* __restrict__ edst,
    int* __restrict__ gcur, uint2* __restrict__ ebuf, int nb) {
  int* lcount = (int*)ldsraw;                 // 4KB, later reused as lofs
  int* lofs   = (int*)ldsraw;                 // alias
  int* lexcl  = (int*)(ldsraw + 4096);        // 4KB
  int* lbase  = (int*)(ldsraw + 8192);        // 4KB
  int* ss     = (int*)(ldsraw + 12288);       // 1KB
  uint2* stage = (uint2*)(ldsraw + 13312);    // 16KB -> total 29696
  const int t = threadIdx.x;
  for (int b = t; b < 1024; b += 256) lcount[b] = 0;
  __syncthreads();
  const int e0 = chunk * 2048;
  uint2 ed[8];
  #pragma unroll
  for (int j = 0; j < 8; ++j) {
    int e = e0 + j * 256 + t;
    ed[j].x = (unsigned)esrc[e];
    ed[j].y = (unsigned)edst[e];
    atomicAdd(&lcount[ed[j].y >> 7], 1);
  }
  __syncthreads();
  int c[4]; int mysum = 0;
  #pragma unroll
  for (int j = 0; j < 4; ++j) { c[j] = lcount[t * 4 + j]; mysum += c[j]; }
  ss[t] = mysum;
  __syncthreads();
  for (int o = 1; o < 256; o <<= 1) {
    int x = (t >= o) ? ss[t - o] : 0;
    __syncthreads();
    ss[t] += x;
    __syncthreads();
  }
  int run = ss[t] - mysum;
  #pragma unroll
  for (int j = 0; j < 4; ++j) { lexcl[t * 4 + j] = run; run += c[j]; }
  __syncthreads();
  for (int b = t; b < 1024; b += 256) {
    int cnt = lcount[b];                       // read before alias write
    lbase[b] = (b < nb && cnt) ? atomicAdd(&gcur[b], cnt) : 0;
    lofs[b]  = lexcl[b];                       // overwrites lcount[b]
  }
  __syncthreads();
  #pragma unroll
  for (int j = 0; j < 8; ++j) {
    int b = ed[j].y >> 7;
    int p = atomicAdd(&lofs[b], 1);
    stage[p] = ed[j];
  }
  __syncthreads();
  for (int i = t; i < 2048; i += 256) {
    uint2 v = stage[i];
    int b = v.y >> 7;
    ebuf[lbase[b] + (i - lexcl[b])] = v;
  }
}

// ---------------------------------------------------------------------------
// fusedA: dual_gemm (Q:2048, C:1024 tiles) || bucketA (QC:512, CQ:512 chunks).
// LDS exactly 32768B -> 5 blocks/CU.
// ---------------------------------------------------------------------------
__global__ __launch_bounds__(256, 4) void fusedA(
    const float* __restrict__ HQ, const float* __restrict__ lngQ,
    const float* __restrict__ lnbQ, const bf16* __restrict__ WresQ,
    const bf16* __restrict__ WrelQ, const float* __restrict__ degQ,
    bf16* __restrict__ projQ, bf16* __restrict__ xnQ,
    const float* __restrict__ HC, const float* __restrict__ lngC,
    const float* __restrict__ lnbC, const bf16* __restrict__ WresC,
    const bf16* __restrict__ WrelC, const float* __restrict__ degC,
    bf16* __restrict__ projC, bf16* __restrict__ xnC,
    const int* __restrict__ eQCs, const int* __restrict__ eQCd,
    int* __restrict__ gcurQC, uint2* __restrict__ ebufQC,
    const int* __restrict__ eCQs, const int* __restrict__ eCQd,
    int* __restrict__ gcurCQ, uint2* __restrict__ ebufCQ) {
  __shared__ __align__(16) unsigned char lds[32768];
  int bid = blockIdx.x;
  if (bid < 2048) {
    dual_tile(lds, bid, HQ, lngQ, lnbQ, WresQ, WrelQ, degQ, projQ, xnQ);
  } else if (bid < 3072) {
    dual_tile(lds, bid - 2048, HC, lngC, lnbC, WresC, WrelC, degC, projC, xnC);
  } else if (bid < 3584) {
    bucketA_chunk(lds, bid - 3072, eQCs, eQCd, gcurQC, ebufQC, 512);
  } else {
    bucketA_chunk(lds, bid - 3584, eCQs, eCQd, gcurCQ, ebufCQ, 1024);
  }
}

// ---------------------------------------------------------------------------
// mlp_fused2 (R14-exact, measured 80us): out = proj + GELU([proj|msg]@W1+b1)
// @W2 + b2. 64-row tile, 4 waves, 32KB LDS, (256,4) (=(256,5) spills, R13).
// Residual from global (LDS variant +15us, R12); direct scalar f32 stores
// (LDS-staged f32-out spilled, R15). Swizzle (r&7): 2-way conflicts free.
// ---------------------------------------------------------------------------
__global__ __launch_bounds__(256, 4) void mlp_fused2(
    const bf16* __restrict__ projQ, const bf16* __restrict__ msgQ,
    const bf16* __restrict__ W1Q, const float* __restrict__ b1Q,
    const bf16* __restrict__ W2Q, const float* __restrict__ b2Q,
    float* __restrict__ outQ, int splitQ,
    const bf16* __restrict__ projC, const bf16* __restrict__ msgC,
    const bf16* __restrict__ W1C, const float* __restrict__ b1C,
    const bf16* __restrict__ W2C, const float* __restrict__ b2C,
    float* __restrict__ outC) {
  __shared__ __align__(16) unsigned char lds[32768];
  const bf16 *proj, *msg, *W1p, *W2p;
  const float *b1, *b2;
  float* out;
  int bid = blockIdx.x;
  if (bid < splitQ) {
    proj = projQ; msg = msgQ; W1p = W1Q; b1 = b1Q; W2p = W2Q; b2 = b2Q; out = outQ;
  } else {
    bid -= splitQ;
    proj = projC; msg = msgC; W1p = W1C; b1 = b1C; W2p = W2C; b2 = b2C; out = outC;
  }
  const int tid = threadIdx.x;
  const int row0 = bid * 64;
  const int wid = tid >> 6, lane = tid & 63;

  // stage A = [proj | msg], 64 rows x 512B
  #pragma unroll
  for (int it = 0; it < 8; ++it) {
    int lin = it * 256 + tid;
    int r = lin >> 5;
    int cb = (lin & 31) * 16;
    const bf16* src = (cb < 256) ? (proj + (size_t)(row0 + r) * 128)
                                 : (msg + (size_t)(row0 + r) * 128 - 128);
    bf16x8 v = *(const bf16x8*)((const char*)src + cb);
    *(bf16x8*)(lds + r * 512 + (cb ^ ((r & 7) << 4))) = v;
  }
  __syncthreads();

  // phase 1: h[64][256] = A @ W1 (K=256); wave w covers cols w*64..+63
  f32x4 acc1[4][4] = {};
  #pragma unroll
  for (int kk = 0; kk < 8; ++kk) {
    const int kb = kk * 64 + (lane >> 4) * 16;
    bf16x8 af[4], bfv[4];
    #pragma unroll
    for (int fc = 0; fc < 4; ++fc) {
      int cblk = wid * 4 + fc;
      bfv[fc] = *(const bf16x8*)(W1p + ((size_t)(cblk * 8 + kk) * 64 + lane) * 8);
    }
    #pragma unroll
    for (int fr = 0; fr < 4; ++fr) {
      int ar = fr * 16 + (lane & 15);
      af[fr] = *(const bf16x8*)(lds + ar * 512 + (kb ^ ((ar & 7) << 4)));
    }
    #pragma unroll
    for (int fr = 0; fr < 4; ++fr)
      #pragma unroll
      for (int fc = 0; fc < 4; ++fc)
        acc1[fr][fc] = __builtin_amdgcn_mfma_f32_16x16x32_bf16(
            af[fr], bfv[fc], acc1[fr][fc], 0, 0, 0);
  }
  __syncthreads();   // all A reads done -> safe to overwrite with h

  // GELU + b1 -> h panel (64 rows x 512B, same swizzle)
  {
    const int rb = (lane >> 4) * 4;
    const int cb0 = wid * 64 + (lane & 15);
    #pragma unroll
    for (int fc = 0; fc < 4; ++fc) {
      int col = cb0 + fc * 16;
      float bv = b1[col];
      #pragma unroll
      for (int fr = 0; fr < 4; ++fr) {
        #pragma unroll
        for (int r = 0; r < 4; ++r) {
          int row = rb + fr * 16 + r;
          float x = acc1[fr][fc][r] + bv;
          float u2 = 1.5957691216057308f * (x + 0.044715f * x * x * x);
          float e = __expf(u2);
          x = 0.5f * x * (1.f + (1.f - 2.f / (e + 1.f)));
          *(bf16*)(lds + row * 512 + ((col * 2) ^ ((row & 7) << 4))) = (bf16)x;
        }
      }
    }
  }
  __syncthreads();

  // phase 2: out = proj + h @ W2 + b2; wave grid 2x2 (32x64)
  const int wrow2 = (wid >> 1) * 32;
  const int wcol2 = (wid & 1) * 64;
  f32x4 acc2[2][4] = {};
  #pragma unroll
  for (int kk = 0; kk < 8; ++kk) {
    const int kb = kk * 64 + (lane >> 4) * 16;
    bf16x8 af[2], bfv[4];
    #pragma unroll
    for (int fc = 0; fc < 4; ++fc) {
      int cblk = (wid & 1) * 4 + fc;
      bfv[fc] = *(const bf16x8*)(W2p + ((size_t)(cblk * 8 + kk) * 64 + lane) * 8);
    }
    #pragma unroll
    for (int fr = 0; fr < 2; ++fr) {
      int ar = wrow2 + fr * 16 + (lane & 15);
      af[fr] = *(const bf16x8*)(lds + ar * 512 + (kb ^ ((ar & 7) << 4)));
    }
    #pragma unroll
    for (int fr = 0; fr < 2; ++fr)
      #pragma unroll
      for (int fc = 0; fc < 4; ++fc)
        acc2[fr][fc] = __builtin_amdgcn_mfma_f32_16x16x32_bf16(
            af[fr], bfv[fc], acc2[fr][fc], 0, 0, 0);
  }
  const int rbase = wrow2 + (lane >> 4) * 4;
  const int cbase = wcol2 + (lane & 15);
  #pragma unroll
  for (int fr = 0; fr < 2; ++fr) {
    #pragma unroll
    for (int fc = 0; fc < 4; ++fc) {
      int col = cbase + fc * 16;
      float bv = b2[col];
      #pragma unroll
      for (int r = 0; r < 4; ++r) {
        int row = row0 + rbase + fr * 16 + r;
        out[(size_t)row * 128 + col] =
            acc2[fr][fc][r] + bv + (float)proj[(size_t)row * 128 + col];
      }
    }
  }
}

// ---------------------------------------------------------------------------
// bucket_scan: exclusive scan over both bucket-count arrays -> bases + cursors.
// ---------------------------------------------------------------------------
__global__ __launch_bounds__(1024) void bucket_scan(
    const int* __restrict__ bcnt,
    int* __restrict__ baseQC, int* __restrict__ gcurQC,
    int* __restrict__ baseCQ, int* __restrict__ gcurCQ) {
  __shared__ int ss[1024];
  const int t = threadIdx.x;
  int v = (t < 512) ? bcnt[t] : 0;
  ss[t] = v;
  __syncthreads();
  for (int o = 1; o < 1024; o <<= 1) {
    int x = (t >= o) ? ss[t - o] : 0;
    __syncthreads();
    ss[t] += x;
    __syncthreads();
  }
  if (t < 512) { int e = ss[t] - v; baseQC[t] = e; gcurQC[t] = e; }
  if (t == 0) baseQC[512] = En;
  __syncthreads();
  int v2 = bcnt[512 + t];
  ss[t] = v2;
  __syncthreads();
  for (int o = 1; o < 1024; o <<= 1) {
    int x = (t >= o) ? ss[t - o] : 0;
    __syncthreads();
    ss[t] += x;
    __syncthreads();
  }
  { int e = ss[t] - v2; baseCQ[t] = e; gcurCQ[t] = e; }
  if (t == 0) baseCQ[1024] = En;
}

// ---------------------------------------------------------------------------
// bucketB22: merged Q+C. Per-bucket deg-scan -> offs; fill csr via INT LDS
// atomics (csr window contiguous, L2-hot).
// ---------------------------------------------------------------------------
__global__ __launch_bounds__(256) void bucketB22(
    const uint2* __restrict__ ebufQ, const int* __restrict__ bbaseQ,
    const float* __restrict__ degQ, int* __restrict__ offsQ,
    int* __restrict__ csrQ, int splitQ,
    const uint2* __restrict__ ebufC, const int* __restrict__ bbaseC,
    const float* __restrict__ degC, int* __restrict__ offsC,
    int* __restrict__ csrC) {
  __shared__ int sdeg[128];
  __shared__ int lcur[128];
  const uint2* ebuf; const int* bbase; const float* degdst; int* offs; int* csr;
  int b = blockIdx.x;
  if (b < splitQ) { ebuf = ebufQ; bbase = bbaseQ; degdst = degQ; offs = offsQ; csr = csrQ; }
  else { b -= splitQ; ebuf = ebufC; bbase = bbaseC; degdst = degC; offs = offsC; csr = csrC; }
  const int t = threadIdx.x;
  const int base = bbase[b], end = bbase[b + 1];
  int myv = 0;
  if (t < 128) {
    myv = (int)(degdst[(size_t)b * 128 + t] + 0.5f);
    sdeg[t] = myv;
  }
  __syncthreads();
  for (int o = 1; o < 128; o <<= 1) {
    int x = (t < 128 && t >= o) ? sdeg[t - o] : 0;
    __syncthreads();
    if (t < 128) sdeg[t] += x;
    __syncthreads();
  }
  if (t < 128) {
    int excl = sdeg[t] - myv;
    lcur[t] = excl;
    offs[(size_t)b * 128 + t] = base + excl;
  }
  __syncthreads();
  for (int i = base + t; i < end; i += 256) {
    uint2 v = ebuf[i];
    int p = atomicAdd(&lcur[v.y & 127], 1);
    csr[base + p] = (int)v.x;
  }
}

// ---------------------------------------------------------------------------
// gather_one: one relation. One wave per dst row, half-wave pairing,
// 8 edges in flight.
// ---------------------------------------------------------------------------
__global__ __launch_bounds__(256) void gather_one(
    const bf16* __restrict__ Xn, const int* __restrict__ csr,
    const int* __restrict__ offs, const float* __restrict__ degdst,
    const float* __restrict__ gate, bf16* __restrict__ msg) {
  int d = blockIdx.x * 4 + (threadIdx.x >> 6);
  int lane = threadIdx.x & 63;
  int half = lane >> 5, sl = lane & 31;
  float dv = degdst[d];
  int cnt = (int)(dv + 0.5f);
  int start = offs[d];
  float a0 = 0.f, a1 = 0.f, a2 = 0.f, a3 = 0.f;
  int i = 0;
  for (; i + 8 <= cnt; i += 8) {
    int s0 = csr[start + i + half * 4 + 0];
    int s1 = csr[start + i + half * 4 + 1];
    int s2 = csr[start + i + half * 4 + 2];
    int s3 = csr[start + i + half * 4 + 3];
    bf16x4 v0 = *(const bf16x4*)(Xn + (size_t)s0 * 128 + sl * 4);
    bf16x4 v1 = *(const bf16x4*)(Xn + (size_t)s1 * 128 + sl * 4);
    bf16x4 v2 = *(const bf16x4*)(Xn + (size_t)s2 * 128 + sl * 4);
    bf16x4 v3 = *(const bf16x4*)(Xn + (size_t)s3 * 128 + sl * 4);
    a0 += (float)v0[0] + (float)v1[0] + (float)v2[0] + (float)v3[0];
    a1 += (float)v0[1] + (float)v1[1] + (float)v2[1] + (float)v3[1];
    a2 += (float)v0[2] + (float)v1[2] + (float)v2[2] + (float)v3[2];
    a3 += (float)v0[3] + (float)v1[3] + (float)v2[3] + (float)v3[3];
  }
  for (; i + 2 <= cnt; i += 2) {
    int s0 = csr[start + i + half];
    bf16x4 v0 = *(const bf16x4*)(Xn + (size_t)s0 * 128 + sl * 4);
    a0 += (float)v0[0]; a1 += (float)v0[1];
    a2 += (float)v0[2]; a3 += (float)v0[3];
  }
  if (i < cnt && half == 0) {
    int s0 = csr[start + i];
    bf16x4 v0 = *(const bf16x4*)(Xn + (size_t)s0 * 128 + sl * 4);
    a0 += (float)v0[0]; a1 += (float)v0[1];
    a2 += (float)v0[2]; a3 += (float)v0[3];
  }
  a0 += __shfl_xor(a0, 32, 64);
  a1 += __shfl_xor(a1, 32, 64);
  a2 += __shfl_xor(a2, 32, 64);
  a3 += __shfl_xor(a3, 32, 64);
  if (half == 0) {
    float sc = (dv > 0.f ? rsqrtf(dv) : 0.f) * gate[0];
    bf16x4 r;
    r[0] = (bf16)(a0 * sc); r[1] = (bf16)(a1 * sc);
    r[2] = (bf16)(a2 * sc); r[3] = (bf16)(a3 * sc);
    *(bf16x4*)(msg + (size_t)d * 128 + sl * 4) = r;
  }
}

// ---------------------------------------------------------------------------
extern "C" void kernel_launch(void* const* d_in, const int* in_sizes, int n_in,
                              void* d_out, int out_size, void* d_ws, size_t ws_size,
                              hipStream_t stream) {
  const float* H_Q        = (const float*)d_in[0];
  const float* H_C        = (const float*)d_in[1];
  const int*   eQC_src    = (const int*)d_in[2];
  const int*   eQC_dst    = (const int*)d_in[3];
  const int*   eCQ_src    = (const int*)d_in[4];
  const int*   eCQ_dst    = (const int*)d_in[5];
  const float* deg_QC_src = (const float*)d_in[6];
  const float* deg_QC_dst = (const float*)d_in[7];
  const float* deg_CQ_src = (const float*)d_in[8];
  const float* deg_CQ_dst = (const float*)d_in[9];
  const float* ln_g_Q     = (const float*)d_in[10];
  const float* ln_b_Q     = (const float*)d_in[11];
  const float* Wres_Q     = (const float*)d_in[12];
  const float* ln_g_C     = (const float*)d_in[13];
  const float* ln_b_C     = (const float*)d_in[14];
  const float* Wres_C     = (const float*)d_in[15];
  const float* Wrel_QC    = (const float*)d_in[16];
  const float* Wrel_CQ    = (const float*)d_in[17];
  const float* gate_QC    = (const float*)d_in[18];
  const float* gate_CQ    = (const float*)d_in[19];
  const float* W1_Q       = (const float*)d_in[20];
  const float* b1_Q       = (const float*)d_in[21];
  const float* W2_Q       = (const float*)d_in[22];
  const float* b2_Q       = (const float*)d_in[23];
  const float* W1_C       = (const float*)d_in[24];
  const float* b1_C       = (const float*)d_in[25];
  const float* W2_C       = (const float*)d_in[26];
  const float* b2_C       = (const float*)d_in[27];

  char* ws = (char*)d_ws;
  size_t o = 0;
  auto alloc = [&](size_t bytes) -> char* {
    char* p = ws + o;
    o += (bytes + 255) & ~(size_t)255;
    return p;
  };
  bf16* xnbQ = (bf16*)alloc((size_t)NQn * 128 * 2);
  bf16* xnbC = (bf16*)alloc((size_t)NCn * 128 * 2);
  int*  csrQC = (int*)alloc((size_t)En * 4);
  int*  csrCQ = (int*)alloc((size_t)En * 4);
  bf16* projQ = (bf16*)alloc((size_t)NQn * 128 * 2);
  bf16* projC = (bf16*)alloc((size_t)NCn * 128 * 2);
  bf16* msgQ  = (bf16*)alloc((size_t)NQn * 128 * 2);
  bf16* msgC  = (bf16*)alloc((size_t)NCn * 128 * 2);
  uint2* ebufQC = (uint2*)alloc((size_t)En * 8);
  uint2* ebufCQ = (uint2*)alloc((size_t)En * 8);
  bf16* WresQt = (bf16*)alloc(128 * 128 * 2);
  bf16* WresCt = (bf16*)alloc(128 * 128 * 2);
  bf16* WrelQCt = (bf16*)alloc(128 * 128 * 2);
  bf16* WrelCQt = (bf16*)alloc(128 * 128 * 2);
  bf16* W1Qt = (bf16*)alloc(256 * 256 * 2);
  bf16* W1Ct = (bf16*)alloc(256 * 256 * 2);
  bf16* W2Qt = (bf16*)alloc(128 * 256 * 2);
  bf16* W2Ct = (bf16*)alloc(128 * 256 * 2);
  int* bcnt   = (int*)alloc(1536 * 4);
  int* bbaseQC = (int*)alloc(513 * 4);
  int* bbaseCQ = (int*)alloc(1025 * 4);
  int* gcurQC = (int*)alloc(512 * 4);
  int* gcurCQ = (int*)alloc(1024 * 4);
  int* offsQC = (int*)alloc((size_t)NCn * 4);
  int* offsCQ = (int*)alloc((size_t)NQn * 4);

  float* outQ = (float*)d_out;
  float* outC = (float*)d_out + (size_t)NQn * 128;

  // 1. weight pack + bucket histogram (merged), then scan
  prep_kernel<<<2432, 256, 0, stream>>>(
      Wres_Q, WresQt, Wres_C, WresCt, Wrel_QC, WrelQCt, Wrel_CQ, WrelCQt,
      W1_Q, W1Qt, W1_C, W1Ct, W2_Q, W2Qt, W2_C, W2Ct,
      deg_QC_dst, deg_CQ_dst, bcnt);
  bucket_scan<<<1, 1024, 0, stream>>>(bcnt, bbaseQC, gcurQC, bbaseCQ, gcurCQ);

  // 2. fusedA: dual_gemm (Q+C) || bucketA (QC+CQ) — 32KB LDS, 5 blocks/CU
  fusedA<<<4096, 256, 0, stream>>>(
      H_Q, ln_g_Q, ln_b_Q, WresQt, WrelQCt, deg_QC_src, projQ, xnbQ,
      H_C, ln_g_C, ln_b_C, WresCt, WrelCQt, deg_CQ_src, projC, xnbC,
      eQC_src, eQC_dst, gcurQC, ebufQC,
      eCQ_src, eCQ_dst, gcurCQ, ebufCQ);

  // 3. merged CSR build
  bucketB22<<<1536, 256, 0, stream>>>(ebufQC, bbaseQC, deg_QC_dst, offsQC,
                                      csrQC, 512,
                                      ebufCQ, bbaseCQ, deg_CQ_dst, offsCQ,
                                      csrCQ);

  // 4. gathers, split by relation
  gather_one<<<NQn / 4, 256, 0, stream>>>(xnbC, csrCQ, offsCQ, deg_CQ_dst,
                                          gate_CQ, msgQ);
  gather_one<<<NCn / 4, 256, 0, stream>>>(xnbQ, csrQC, offsQC, deg_QC_dst,
                                          gate_QC, msgC);

  // 5. merged fused MLP (R14-exact)
  mlp_fused2<<<NQn / 64 + NCn / 64, 256, 0, stream>>>(
      projQ, msgQ, W1Qt, b1_Q, W2Qt, b2_Q, outQ, NQn / 64,
      projC, msgC, W1Ct, b1_C, W2Ct, b2_C, outC);
}

// Round 18
// 252.675 us; speedup vs baseline: 1.2219x; 1.0411x over previous
//
#include <hip/hip_runtime.h>
#include <stdint.h>

// Problem sizes (fixed by the reference)
#define NQn 131072
#define NCn 65536
#define En  1048576
// D = 128, HID = 256

typedef __bf16 bf16;
typedef __bf16 bf16x2 __attribute__((ext_vector_type(2)));
typedef __bf16 bf16x4 __attribute__((ext_vector_type(4)));
typedef __bf16 bf16x8 __attribute__((ext_vector_type(8)));
typedef float  f32x4  __attribute__((ext_vector_type(4)));
typedef float  f32x2  __attribute__((ext_vector_type(2)));

// ---------------------------------------------------------------------------
// fp8 e4m3 (OCP) helpers: hardware cvt on gfx950, exact software fallback.
// ---------------------------------------------------------------------------
#if defined(__has_builtin)
#if __has_builtin(__builtin_amdgcn_cvt_pk_f32_fp8) && \
    __has_builtin(__builtin_amdgcn_cvt_pk_fp8_f32)
#define HW_FP8 1
#endif
#endif
#ifndef HW_FP8
#define HW_FP8 0
#endif

__device__ __forceinline__ float fp8_dec1(unsigned b) {
  unsigned s = b & 0x80u, em = b & 0x7fu;
  float mag;
  if (em >= 8) {
    mag = __uint_as_float((((em >> 3) + 120) << 23) | ((em & 7) << 20));
  } else {
    mag = (float)em * 0.001953125f;   // subnormal: m * 2^-9
  }
  return s ? -mag : mag;
}

__device__ __forceinline__ unsigned char fp8_enc1(float f) {
  unsigned s = (__float_as_uint(f) >> 24) & 0x80u;
  float a = fabsf(f);
  if (a > 448.f) a = 448.f;
  if (a < 0.0009765625f) return (unsigned char)s;   // below half min-subnormal
  int e; float m = frexpf(a, &e);                   // a = m*2^e, m in [0.5,1)
  float q = rintf(m * 16.f);                        // RNE to 1.mmm x 2^(e-1)
  if (q >= 16.f) { q = 8.f; e += 1; }
  int ee = e - 1 + 7;
  if (ee <= 0) {
    float sq = rintf(a * 512.f);
    return (unsigned char)(s | (unsigned)sq);
  }
  return (unsigned char)(s | ((unsigned)ee << 3) | ((unsigned)q & 7));
}

__device__ __forceinline__ void fp8x4_acc(unsigned w, float& a0, float& a1,
                                          float& a2, float& a3) {
#if HW_FP8
  f32x2 lo = __builtin_amdgcn_cvt_pk_f32_fp8((int)w, false);
  f32x2 hi = __builtin_amdgcn_cvt_pk_f32_fp8((int)w, true);
  a0 += lo[0]; a1 += lo[1]; a2 += hi[0]; a3 += hi[1];
#else
  a0 += fp8_dec1(w & 0xff);
  a1 += fp8_dec1((w >> 8) & 0xff);
  a2 += fp8_dec1((w >> 16) & 0xff);
  a3 += fp8_dec1((w >> 24) & 0xff);
#endif
}

__device__ __forceinline__ unsigned fp8x4_pack(float f0, float f1,
                                               float f2, float f3) {
#if HW_FP8
  int v = __builtin_amdgcn_cvt_pk_fp8_f32(f0, f1, 0, false);
  v = __builtin_amdgcn_cvt_pk_fp8_f32(f2, f3, v, true);
  return (unsigned)v;
#else
  return (unsigned)fp8_enc1(f0) | ((unsigned)fp8_enc1(f1) << 8) |
         ((unsigned)fp8_enc1(f2) << 16) | ((unsigned)fp8_enc1(f3) << 24);
#endif
}

// ---------------------------------------------------------------------------
// prep_kernel: weight fragment-pack (blocks 0..2047) + bucket histogram
// (blocks 2048..2431).
// ---------------------------------------------------------------------------
__global__ __launch_bounds__(256) void prep_kernel(
    const float* __restrict__ w0, bf16* __restrict__ t0,
    const float* __restrict__ w1, bf16* __restrict__ t1,
    const float* __restrict__ w2, bf16* __restrict__ t2,
    const float* __restrict__ w3, bf16* __restrict__ t3,
    const float* __restrict__ w4, bf16* __restrict__ t4,
    const float* __restrict__ w5, bf16* __restrict__ t5,
    const float* __restrict__ w6, bf16* __restrict__ t6,
    const float* __restrict__ w7, bf16* __restrict__ t7,
    const float* __restrict__ degQC, const float* __restrict__ degCQ,
    int* __restrict__ bcnt) {
  int blk = blockIdx.x;
  if (blk >= 2048) {
    int w = ((blk - 2048) * 256 + threadIdx.x) >> 6;
    int lane = threadIdx.x & 63;
    const float* deg = (w < 512) ? (degQC + (size_t)w * 128)
                                 : (degCQ + (size_t)(w - 512) * 128);
    float s = deg[lane] + deg[lane + 64];
    #pragma unroll
    for (int o = 32; o; o >>= 1) s += __shfl_xor(s, o, 64);
    if (lane == 0) bcnt[w] = (int)(s + 0.5f);
    return;
  }
  int wsel = blk >> 8;
  const float* W; bf16* T; int K, M;
  switch (wsel) {
    case 0: W = w0; T = t0; K = 128; M = 128; break;
    case 1: W = w1; T = t1; K = 128; M = 128; break;
    case 2: W = w2; T = t2; K = 128; M = 128; break;
    case 3: W = w3; T = t3; K = 128; M = 128; break;
    case 4: W = w4; T = t4; K = 256; M = 256; break;
    case 5: W = w5; T = t5; K = 256; M = 256; break;
    case 6: W = w6; T = t6; K = 256; M = 128; break;
    default: W = w7; T = t7; K = 256; M = 128; break;
  }
  int t = (blk & 255) * 256 + threadIdx.x;
  if (t >= K * M) return;
  int KB = K >> 5;
  int frag = t >> 9, within = t & 511;
  int lane = within >> 3, j = within & 7;
  int mb = frag / KB, kb = frag % KB;
  int m = mb * 16 + (lane & 15);
  int k = kb * 32 + (lane >> 4) * 8 + j;
  T[t] = (bf16)W[k * M + m];
}

// ---------------------------------------------------------------------------
// dual_tile: one 64-row tile: proj = LN(H)@Wres (bf16 out), xn = (H@Wrel)*
// deg^-1/2 (fp8 e4m3 out — halves gather traffic). LDS 32KB.
// ---------------------------------------------------------------------------
__device__ __forceinline__ void dual_tile(
    unsigned char* lds, int bid,
    const float* __restrict__ H, const float* __restrict__ lng,
    const float* __restrict__ lnb, const bf16* __restrict__ Wres,
    const bf16* __restrict__ Wrel, const float* __restrict__ degsrc,
    bf16* __restrict__ proj, unsigned char* __restrict__ xn) {
  const int tid = threadIdx.x;
  const int row0 = bid * 64;
  const int wid = tid >> 6, lane = tid & 63;
  const int wrow = (wid >> 1) * 32, wcol = (wid & 1) * 64;

  #pragma unroll
  for (int it = 0; it < 8; ++it) {
    int lin = it * 256 + tid;
    int r = lin >> 5;
    int c = (lin & 31) * 4;
    float4 v = *(const float4*)(H + (size_t)(row0 + r) * 128 + c);
    float s = v.x + v.y + v.z + v.w;
    #pragma unroll
    for (int o = 16; o; o >>= 1) s += __shfl_xor(s, o, 64);
    float mean = s * (1.0f / 128.0f);
    float d0 = v.x - mean, d1 = v.y - mean, d2 = v.z - mean, d3 = v.w - mean;
    float q = d0 * d0 + d1 * d1 + d2 * d2 + d3 * d3;
    #pragma unroll
    for (int o = 16; o; o >>= 1) q += __shfl_xor(q, o, 64);
    float rsv = rsqrtf(q * (1.0f / 128.0f) + 1e-5f);
    float4 gg = *(const float4*)(lng + c);
    float4 bb = *(const float4*)(lnb + c);
    bf16x4 w;
    w[0] = (bf16)(d0 * rsv * gg.x + bb.x);
    w[1] = (bf16)(d1 * rsv * gg.y + bb.y);
    w[2] = (bf16)(d2 * rsv * gg.z + bb.z);
    w[3] = (bf16)(d3 * rsv * gg.w + bb.w);
    int off = r * 256 + ((c * 2) ^ ((r & 7) << 4));
    *(bf16x4*)(lds + off) = w;
    bf16x4 rw;
    rw[0] = (bf16)v.x; rw[1] = (bf16)v.y; rw[2] = (bf16)v.z; rw[3] = (bf16)v.w;
    *(bf16x4*)(lds + 16384 + off) = rw;
  }
  __syncthreads();

  const int rloc = wrow + (lane >> 4) * 4;
  const int cloc = wcol + (lane & 15);

  // pass 0: proj = lnh @ Wres
  {
    f32x4 acc[2][4] = {};
    #pragma unroll
    for (int kk = 0; kk < 4; ++kk) {
      const int kb = kk * 64 + (lane >> 4) * 16;
      bf16x8 af[2], bfv[4];
      #pragma unroll
      for (int fc = 0; fc < 4; ++fc) {
        int cblk = (wid & 1) * 4 + fc;
        bfv[fc] = *(const bf16x8*)(Wres + ((size_t)(cblk * 4 + kk) * 64 + lane) * 8);
      }
      #pragma unroll
      for (int fr = 0; fr < 2; ++fr) {
        int ar = wrow + fr * 16 + (lane & 15);
        af[fr] = *(const bf16x8*)(lds + ar * 256 + (kb ^ ((ar & 7) << 4)));
      }
      #pragma unroll
      for (int fr = 0; fr < 2; ++fr)
        #pragma unroll
        for (int fc = 0; fc < 4; ++fc)
          acc[fr][fc] = __builtin_amdgcn_mfma_f32_16x16x32_bf16(
              af[fr], bfv[fc], acc[fr][fc], 0, 0, 0);
    }
    __syncthreads();
    #pragma unroll
    for (int fr = 0; fr < 2; ++fr)
      #pragma unroll
      for (int fc = 0; fc < 4; ++fc)
        #pragma unroll
        for (int r = 0; r < 4; ++r) {
          int row = rloc + fr * 16 + r;
          int colb = (cloc + fc * 16) * 2;
          *(bf16*)(lds + row * 256 + (colb ^ ((row & 7) << 4))) =
              (bf16)acc[fr][fc][r];
        }
  }

  // pass 1: xn = (hb @ Wrel) * invsqrt(deg)  (bf16 staged in LDS)
  {
    f32x4 acc[2][4] = {};
    #pragma unroll
    for (int kk = 0; kk < 4; ++kk) {
      const int kb = kk * 64 + (lane >> 4) * 16;
      bf16x8 af[2], bfv[4];
      #pragma unroll
      for (int fc = 0; fc < 4; ++fc) {
        int cblk = (wid & 1) * 4 + fc;
        bfv[fc] = *(const bf16x8*)(Wrel + ((size_t)(cblk * 4 + kk) * 64 + lane) * 8);
      }
      #pragma unroll
      for (int fr = 0; fr < 2; ++fr) {
        int ar = wrow + fr * 16 + (lane & 15);
        af[fr] = *(const bf16x8*)(lds + 16384 + ar * 256 + (kb ^ ((ar & 7) << 4)));
      }
      #pragma unroll
      for (int fr = 0; fr < 2; ++fr)
        #pragma unroll
        for (int fc = 0; fc < 4; ++fc)
          acc[fr][fc] = __builtin_amdgcn_mfma_f32_16x16x32_bf16(
              af[fr], bfv[fc], acc[fr][fc], 0, 0, 0);
    }
    __syncthreads();
    #pragma unroll
    for (int fr = 0; fr < 2; ++fr) {
      float rs[4];
      #pragma unroll
      for (int r = 0; r < 4; ++r) {
        float dv = degsrc[row0 + rloc + fr * 16 + r];
        rs[r] = dv > 0.f ? rsqrtf(dv) : 0.f;
      }
      #pragma unroll
      for (int fc = 0; fc < 4; ++fc)
        #pragma unroll
        for (int r = 0; r < 4; ++r) {
          int row = rloc + fr * 16 + r;
          int colb = (cloc + fc * 16) * 2;
          *(bf16*)(lds + 16384 + row * 256 + (colb ^ ((row & 7) << 4))) =
              (bf16)(acc[fr][fc][r] * rs[r]);
        }
    }
  }
  __syncthreads();

  // coalesced out: proj as bf16x8 (16B), xn converted bf16->fp8 (8B stores)
  #pragma unroll
  for (int it = 0; it < 8; ++it) {
    int lin = it * 256 + tid;
    if (lin < 1024) {
      int r = lin >> 4;
      int cb = (lin & 15) * 16;
      bf16x8 v = *(const bf16x8*)(lds + r * 256 + (cb ^ ((r & 7) << 4)));
      *(bf16x8*)((char*)(proj + (size_t)(row0 + r) * 128) + cb) = v;
    } else {
      int chunk = lin - 1024;
      int r = chunk >> 4;
      int cb = (chunk & 15) * 16;     // byte offset in bf16 row (16B chunk)
      bf16x8 v = *(const bf16x8*)(lds + 16384 + r * 256 + (cb ^ ((r & 7) << 4)));
      unsigned lo = fp8x4_pack((float)v[0], (float)v[1], (float)v[2], (float)v[3]);
      unsigned hi = fp8x4_pack((float)v[4], (float)v[5], (float)v[6], (float)v[7]);
      uint2 o8; o8.x = lo; o8.y = hi;
      *(uint2*)(xn + (size_t)(row0 + r) * 128 + (cb >> 1)) = o8;
    }
  }
}

// ---------------------------------------------------------------------------
// bucketA_chunk: partition one 2048-edge chunk into bucket-grouped ebuf
// (bucket = dst>>7). 29696B LDS (lofs aliases lcount).
// ---------------------------------------------------------------------------
__device__ __forceinline__ void bucketA_chunk(
    unsigned char* ldsraw, int chunk,
    const int* __restrict__ esrc, const int* __restrict__ edst,
    int* __restrict__ gcur, uint2* __restrict__ ebuf, int nb) {
  int* lcount = (int*)ldsraw;
  int* lofs   = (int*)ldsraw;
  int* lexcl  = (int*)(ldsraw + 4096);
  int* lbase  = (int*)(ldsraw + 8192);
  int* ss     = (int*)(ldsraw + 12288);
  uint2* stage = (uint2*)(ldsraw + 13312);
  const int t = threadIdx.x;
  for (int b = t; b < 1024; b += 256) lcount[b] = 0;
  __syncthreads();
  const int e0 = chunk * 2048;
  uint2 ed[8];
  #pragma unroll
  for (int j = 0; j < 8; ++j) {
    int e = e0 + j * 256 + t;
    ed[j].x = (unsigned)esrc[e];
    ed[j].y = (unsigned)edst[e];
    atomicAdd(&lcount[ed[j].y >> 7], 1);
  }
  __syncthreads();
  int c[4]; int mysum = 0;
  #pragma unroll
  for (int j = 0; j < 4; ++j) { c[j] = lcount[t * 4 + j]; mysum += c[j]; }
  ss[t] = mysum;
  __syncthreads();
  for (int o = 1; o < 256; o <<= 1) {
    int x = (t >= o) ? ss[t - o] : 0;
    __syncthreads();
    ss[t] += x;
    __syncthreads();
  }
  int run = ss[t] - mysum;
  #pragma unroll
  for (int j = 0; j < 4; ++j) { lexcl[t * 4 + j] = run; run += c[j]; }
  __syncthreads();
  for (int b = t; b < 1024; b += 256) {
    int cnt = lcount[b];
    lbase[b] = (b < nb && cnt) ? atomicAdd(&gcur[b], cnt) : 0;
    lofs[b]  = lexcl[b];
  }
  __syncthreads();
  #pragma unroll
  for (int j = 0; j < 8; ++j) {
    int b = ed[j].y >> 7;
    int p = atomicAdd(&lofs[b], 1);
    stage[p] = ed[j];
  }
  __syncthreads();
  for (int i = t; i < 2048; i += 256) {
    uint2 v = stage[i];
    int b = v.y >> 7;
    ebuf[lbase[b] + (i - lexcl[b])] = v;
  }
}

// ---------------------------------------------------------------------------
// fusedA: dual_gemm (Q:2048, C:1024 tiles) || bucketA (QC:512, CQ:512 chunks).
// ---------------------------------------------------------------------------
__global__ __launch_bounds__(256, 4) void fusedA(
    const float* __restrict__ HQ, const float* __restrict__ lngQ,
    const float* __restrict__ lnbQ, const bf16* __restrict__ WresQ,
    const bf16* __restrict__ WrelQ, const float* __restrict__ degQ,
    bf16* __restrict__ projQ, unsigned char* __restrict__ xnQ,
    const float* __restrict__ HC, const float* __restrict__ lngC,
    const float* __restrict__ lnbC, const bf16* __restrict__ WresC,
    const bf16* __restrict__ WrelC, const float* __restrict__ degC,
    bf16* __restrict__ projC, unsigned char* __restrict__ xnC,
    const int* __restrict__ eQCs, const int* __restrict__ eQCd,
    int* __restrict__ gcurQC, uint2* __restrict__ ebufQC,
    const int* __restrict__ eCQs, const int* __restrict__ eCQd,
    int* __restrict__ gcurCQ, uint2* __restrict__ ebufCQ) {
  __shared__ __align__(16) unsigned char lds[32768];
  int bid = blockIdx.x;
  if (bid < 2048) {
    dual_tile(lds, bid, HQ, lngQ, lnbQ, WresQ, WrelQ, degQ, projQ, xnQ);
  } else if (bid < 3072) {
    dual_tile(lds, bid - 2048, HC, lngC, lnbC, WresC, WrelC, degC, projC, xnC);
  } else if (bid < 3584) {
    bucketA_chunk(lds, bid - 3072, eQCs, eQCd, gcurQC, ebufQC, 512);
  } else {
    bucketA_chunk(lds, bid - 3584, eCQs, eCQd, gcurCQ, ebufCQ, 1024);
  }
}

// ---------------------------------------------------------------------------
// mlp_fused2 (R14-exact): out = proj + GELU([proj|msg]@W1+b1)@W2 + b2.
// ---------------------------------------------------------------------------
__global__ __launch_bounds__(256, 4) void mlp_fused2(
    const bf16* __restrict__ projQ, const bf16* __restrict__ msgQ,
    const bf16* __restrict__ W1Q, const float* __restrict__ b1Q,
    const bf16* __restrict__ W2Q, const float* __restrict__ b2Q,
    float* __restrict__ outQ, int splitQ,
    const bf16* __restrict__ projC, const bf16* __restrict__ msgC,
    const bf16* __restrict__ W1C, const float* __restrict__ b1C,
    const bf16* __restrict__ W2C, const float* __restrict__ b2C,
    float* __restrict__ outC) {
  __shared__ __align__(16) unsigned char lds[32768];
  const bf16 *proj, *msg, *W1p, *W2p;
  const float *b1, *b2;
  float* out;
  int bid = blockIdx.x;
  if (bid < splitQ) {
    proj = projQ; msg = msgQ; W1p = W1Q; b1 = b1Q; W2p = W2Q; b2 = b2Q; out = outQ;
  } else {
    bid -= splitQ;
    proj = projC; msg = msgC; W1p = W1C; b1 = b1C; W2p = W2C; b2 = b2C; out = outC;
  }
  const int tid = threadIdx.x;
  const int row0 = bid * 64;
  const int wid = tid >> 6, lane = tid & 63;

  #pragma unroll
  for (int it = 0; it < 8; ++it) {
    int lin = it * 256 + tid;
    int r = lin >> 5;
    int cb = (lin & 31) * 16;
    const bf16* src = (cb < 256) ? (proj + (size_t)(row0 + r) * 128)
                                 : (msg + (size_t)(row0 + r) * 128 - 128);
    bf16x8 v = *(const bf16x8*)((const char*)src + cb);
    *(bf16x8*)(lds + r * 512 + (cb ^ ((r & 7) << 4))) = v;
  }
  __syncthreads();

  f32x4 acc1[4][4] = {};
  #pragma unroll
  for (int kk = 0; kk < 8; ++kk) {
    const int kb = kk * 64 + (lane >> 4) * 16;
    bf16x8 af[4], bfv[4];
    #pragma unroll
    for (int fc = 0; fc < 4; ++fc) {
      int cblk = wid * 4 + fc;
      bfv[fc] = *(const bf16x8*)(W1p + ((size_t)(cblk * 8 + kk) * 64 + lane) * 8);
    }
    #pragma unroll
    for (int fr = 0; fr < 4; ++fr) {
      int ar = fr * 16 + (lane & 15);
      af[fr] = *(const bf16x8*)(lds + ar * 512 + (kb ^ ((ar & 7) << 4)));
    }
    #pragma unroll
    for (int fr = 0; fr < 4; ++fr)
      #pragma unroll
      for (int fc = 0; fc < 4; ++fc)
        acc1[fr][fc] = __builtin_amdgcn_mfma_f32_16x16x32_bf16(
            af[fr], bfv[fc], acc1[fr][fc], 0, 0, 0);
  }
  __syncthreads();

  {
    const int rb = (lane >> 4) * 4;
    const int cb0 = wid * 64 + (lane & 15);
    #pragma unroll
    for (int fc = 0; fc < 4; ++fc) {
      int col = cb0 + fc * 16;
      float bv = b1[col];
      #pragma unroll
      for (int fr = 0; fr < 4; ++fr) {
        #pragma unroll
        for (int r = 0; r < 4; ++r) {
          int row = rb + fr * 16 + r;
          float x = acc1[fr][fc][r] + bv;
          float u2 = 1.5957691216057308f * (x + 0.044715f * x * x * x);
          float e = __expf(u2);
          x = 0.5f * x * (1.f + (1.f - 2.f / (e + 1.f)));
          *(bf16*)(lds + row * 512 + ((col * 2) ^ ((row & 7) << 4))) = (bf16)x;
        }
      }
    }
  }
  __syncthreads();

  const int wrow2 = (wid >> 1) * 32;
  const int wcol2 = (wid & 1) * 64;
  f32x4 acc2[2][4] = {};
  #pragma unroll
  for (int kk = 0; kk < 8; ++kk) {
    const int kb = kk * 64 + (lane >> 4) * 16;
    bf16x8 af[2], bfv[4];
    #pragma unroll
    for (int fc = 0; fc < 4; ++fc) {
      int cblk = (wid & 1) * 4 + fc;
      bfv[fc] = *(const bf16x8*)(W2p + ((size_t)(cblk * 8 + kk) * 64 + lane) * 8);
    }
    #pragma unroll
    for (int fr = 0; fr < 2; ++fr) {
      int ar = wrow2 + fr * 16 + (lane & 15);
      af[fr] = *(const bf16x8*)(lds + ar * 512 + (kb ^ ((ar & 7) << 4)));
    }
    #pragma unroll
    for (int fr = 0; fr < 2; ++fr)
      #pragma unroll
      for (int fc = 0; fc < 4; ++fc)
        acc2[fr][fc] = __builtin_amdgcn_mfma_f32_16x16x32_bf16(
            af[fr], bfv[fc], acc2[fr][fc], 0, 0, 0);
  }
  const int rbase = wrow2 + (lane >> 4) * 4;
  const int cbase = wcol2 + (lane & 15);
  #pragma unroll
  for (int fr = 0; fr < 2; ++fr) {
    #pragma unroll
    for (int fc = 0; fc < 4; ++fc) {
      int col = cbase + fc * 16;
      float bv = b2[col];
      #pragma unroll
      for (int r = 0; r < 4; ++r) {
        int row = row0 + rbase + fr * 16 + r;
        out[(size_t)row * 128 + col] =
            acc2[fr][fc][r] + bv + (float)proj[(size_t)row * 128 + col];
      }
    }
  }
}

// ---------------------------------------------------------------------------
// bucket_scan + bucketB22 (unchanged)
// ---------------------------------------------------------------------------
__global__ __launch_bounds__(1024) void bucket_scan(
    const int* __restrict__ bcnt,
    int* __restrict__ baseQC, int* __restrict__ gcurQC,
    int* __restrict__ baseCQ, int* __restrict__ gcurCQ) {
  __shared__ int ss[1024];
  const int t = threadIdx.x;
  int v = (t < 512) ? bcnt[t] : 0;
  ss[t] = v;
  __syncthreads();
  for (int o = 1; o < 1024; o <<= 1) {
    int x = (t >= o) ? ss[t - o] : 0;
    __syncthreads();
    ss[t] += x;
    __syncthreads();
  }
  if (t < 512) { int e = ss[t] - v; baseQC[t] = e; gcurQC[t] = e; }
  if (t == 0) baseQC[512] = En;
  __syncthreads();
  int v2 = bcnt[512 + t];
  ss[t] = v2;
  __syncthreads();
  for (int o = 1; o < 1024; o <<= 1) {
    int x = (t >= o) ? ss[t - o] : 0;
    __syncthreads();
    ss[t] += x;
    __syncthreads();
  }
  { int e = ss[t] - v2; baseCQ[t] = e; gcurCQ[t] = e; }
  if (t == 0) baseCQ[1024] = En;
}

__global__ __launch_bounds__(256) void bucketB22(
    const uint2* __restrict__ ebufQ, const int* __restrict__ bbaseQ,
    const float* __restrict__ degQ, int* __restrict__ offsQ,
    int* __restrict__ csrQ, int splitQ,
    const uint2* __restrict__ ebufC, const int* __restrict__ bbaseC,
    const float* __restrict__ degC, int* __restrict__ offsC,
    int* __restrict__ csrC) {
  __shared__ int sdeg[128];
  __shared__ int lcur[128];
  const uint2* ebuf; const int* bbase; const float* degdst; int* offs; int* csr;
  int b = blockIdx.x;
  if (b < splitQ) { ebuf = ebufQ; bbase = bbaseQ; degdst = degQ; offs = offsQ; csr = csrQ; }
  else { b -= splitQ; ebuf = ebufC; bbase = bbaseC; degdst = degC; offs = offsC; csr = csrC; }
  const int t = threadIdx.x;
  const int base = bbase[b], end = bbase[b + 1];
  int myv = 0;
  if (t < 128) {
    myv = (int)(degdst[(size_t)b * 128 + t] + 0.5f);
    sdeg[t] = myv;
  }
  __syncthreads();
  for (int o = 1; o < 128; o <<= 1) {
    int x = (t < 128 && t >= o) ? sdeg[t - o] : 0;
    __syncthreads();
    if (t < 128) sdeg[t] += x;
    __syncthreads();
  }
  if (t < 128) {
    int excl = sdeg[t] - myv;
    lcur[t] = excl;
    offs[(size_t)b * 128 + t] = base + excl;
  }
  __syncthreads();
  for (int i = base + t; i < end; i += 256) {
    uint2 v = ebuf[i];
    int p = atomicAdd(&lcur[v.y & 127], 1);
    csr[base + p] = (int)v.x;
  }
}

// ---------------------------------------------------------------------------
// gather_one: fp8 Xn rows (128B). One wave per dst row, half-wave pairing,
// 8 edges in flight; hw fp8->f32 conversion.
// ---------------------------------------------------------------------------
__global__ __launch_bounds__(256) void gather_one(
    const unsigned char* __restrict__ Xn, const int* __restrict__ csr,
    const int* __restrict__ offs, const float* __restrict__ degdst,
    const float* __restrict__ gate, bf16* __restrict__ msg) {
  int d = blockIdx.x * 4 + (threadIdx.x >> 6);
  int lane = threadIdx.x & 63;
  int half = lane >> 5, sl = lane & 31;
  float dv = degdst[d];
  int cnt = (int)(dv + 0.5f);
  int start = offs[d];
  float a0 = 0.f, a1 = 0.f, a2 = 0.f, a3 = 0.f;
  int i = 0;
  for (; i + 8 <= cnt; i += 8) {
    int s0 = csr[start + i + half * 4 + 0];
    int s1 = csr[start + i + half * 4 + 1];
    int s2 = csr[start + i + half * 4 + 2];
    int s3 = csr[start + i + half * 4 + 3];
    unsigned w0 = *(const unsigned*)(Xn + (size_t)s0 * 128 + sl * 4);
    unsigned w1 = *(const unsigned*)(Xn + (size_t)s1 * 128 + sl * 4);
    unsigned w2 = *(const unsigned*)(Xn + (size_t)s2 * 128 + sl * 4);
    unsigned w3 = *(const unsigned*)(Xn + (size_t)s3 * 128 + sl * 4);
    fp8x4_acc(w0, a0, a1, a2, a3);
    fp8x4_acc(w1, a0, a1, a2, a3);
    fp8x4_acc(w2, a0, a1, a2, a3);
    fp8x4_acc(w3, a0, a1, a2, a3);
  }
  for (; i + 2 <= cnt; i += 2) {
    int s0 = csr[start + i + half];
    unsigned w0 = *(const unsigned*)(Xn + (size_t)s0 * 128 + sl * 4);
    fp8x4_acc(w0, a0, a1, a2, a3);
  }
  if (i < cnt && half == 0) {
    int s0 = csr[start + i];
    unsigned w0 = *(const unsigned*)(Xn + (size_t)s0 * 128 + sl * 4);
    fp8x4_acc(w0, a0, a1, a2, a3);
  }
  a0 += __shfl_xor(a0, 32, 64);
  a1 += __shfl_xor(a1, 32, 64);
  a2 += __shfl_xor(a2, 32, 64);
  a3 += __shfl_xor(a3, 32, 64);
  if (half == 0) {
    float sc = (dv > 0.f ? rsqrtf(dv) : 0.f) * gate[0];
    bf16x4 r;
    r[0] = (bf16)(a0 * sc); r[1] = (bf16)(a1 * sc);
    r[2] = (bf16)(a2 * sc); r[3] = (bf16)(a3 * sc);
    *(bf16x4*)(msg + (size_t)d * 128 + sl * 4) = r;
  }
}

// ---------------------------------------------------------------------------
extern "C" void kernel_launch(void* const* d_in, const int* in_sizes, int n_in,
                              void* d_out, int out_size, void* d_ws, size_t ws_size,
                              hipStream_t stream) {
  const float* H_Q        = (const float*)d_in[0];
  const float* H_C        = (const float*)d_in[1];
  const int*   eQC_src    = (const int*)d_in[2];
  const int*   eQC_dst    = (const int*)d_in[3];
  const int*   eCQ_src    = (const int*)d_in[4];
  const int*   eCQ_dst    = (const int*)d_in[5];
  const float* deg_QC_src = (const float*)d_in[6];
  const float* deg_QC_dst = (const float*)d_in[7];
  const float* deg_CQ_src = (const float*)d_in[8];
  const float* deg_CQ_dst = (const float*)d_in[9];
  const float* ln_g_Q     = (const float*)d_in[10];
  const float* ln_b_Q     = (const float*)d_in[11];
  const float* Wres_Q     = (const float*)d_in[12];
  const float* ln_g_C     = (const float*)d_in[13];
  const float* ln_b_C     = (const float*)d_in[14];
  const float* Wres_C     = (const float*)d_in[15];
  const float* Wrel_QC    = (const float*)d_in[16];
  const float* Wrel_CQ    = (const float*)d_in[17];
  const float* gate_QC    = (const float*)d_in[18];
  const float* gate_CQ    = (const float*)d_in[19];
  const float* W1_Q       = (const float*)d_in[20];
  const float* b1_Q       = (const float*)d_in[21];
  const float* W2_Q       = (const float*)d_in[22];
  const float* b2_Q       = (const float*)d_in[23];
  const float* W1_C       = (const float*)d_in[24];
  const float* b1_C       = (const float*)d_in[25];
  const float* W2_C       = (const float*)d_in[26];
  const float* b2_C       = (const float*)d_in[27];

  char* ws = (char*)d_ws;
  size_t o = 0;
  auto alloc = [&](size_t bytes) -> char* {
    char* p = ws + o;
    o += (bytes + 255) & ~(size_t)255;
    return p;
  };
  unsigned char* xnbQ = (unsigned char*)alloc((size_t)NQn * 128);
  unsigned char* xnbC = (unsigned char*)alloc((size_t)NCn * 128);
  int*  csrQC = (int*)alloc((size_t)En * 4);
  int*  csrCQ = (int*)alloc((size_t)En * 4);
  bf16* projQ = (bf16*)alloc((size_t)NQn * 128 * 2);
  bf16* projC = (bf16*)alloc((size_t)NCn * 128 * 2);
  bf16* msgQ  = (bf16*)alloc((size_t)NQn * 128 * 2);
  bf16* msgC  = (bf16*)alloc((size_t)NCn * 128 * 2);
  uint2* ebufQC = (uint2*)alloc((size_t)En * 8);
  uint2* ebufCQ = (uint2*)alloc((size_t)En * 8);
  bf16* WresQt = (bf16*)alloc(128 * 128 * 2);
  bf16* WresCt = (bf16*)alloc(128 * 128 * 2);
  bf16* WrelQCt = (bf16*)alloc(128 * 128 * 2);
  bf16* WrelCQt = (bf16*)alloc(128 * 128 * 2);
  bf16* W1Qt = (bf16*)alloc(256 * 256 * 2);
  bf16* W1Ct = (bf16*)alloc(256 * 256 * 2);
  bf16* W2Qt = (bf16*)alloc(128 * 256 * 2);
  bf16* W2Ct = (bf16*)alloc(128 * 256 * 2);
  int* bcnt   = (int*)alloc(1536 * 4);
  int* bbaseQC = (int*)alloc(513 * 4);
  int* bbaseCQ = (int*)alloc(1025 * 4);
  int* gcurQC = (int*)alloc(512 * 4);
  int* gcurCQ = (int*)alloc(1024 * 4);
  int* offsQC = (int*)alloc((size_t)NCn * 4);
  int* offsCQ = (int*)alloc((size_t)NQn * 4);

  float* outQ = (float*)d_out;
  float* outC = (float*)d_out + (size_t)NQn * 128;

  // 1. weight pack + bucket histogram (merged), then scan
  prep_kernel<<<2432, 256, 0, stream>>>(
      Wres_Q, WresQt, Wres_C, WresCt, Wrel_QC, WrelQCt, Wrel_CQ, WrelCQt,
      W1_Q, W1Qt, W1_C, W1Ct, W2_Q, W2Qt, W2_C, W2Ct,
      deg_QC_dst, deg_CQ_dst, bcnt);
  bucket_scan<<<1, 1024, 0, stream>>>(bcnt, bbaseQC, gcurQC, bbaseCQ, gcurCQ);

  // 2. fusedA: dual_gemm (Q+C, fp8 xn out) || bucketA (QC+CQ)
  fusedA<<<4096, 256, 0, stream>>>(
      H_Q, ln_g_Q, ln_b_Q, WresQt, WrelQCt, deg_QC_src, projQ, xnbQ,
      H_C, ln_g_C, ln_b_C, WresCt, WrelCQt, deg_CQ_src, projC, xnbC,
      eQC_src, eQC_dst, gcurQC, ebufQC,
      eCQ_src, eCQ_dst, gcurCQ, ebufCQ);

  // 3. merged CSR build
  bucketB22<<<1536, 256, 0, stream>>>(ebufQC, bbaseQC, deg_QC_dst, offsQC,
                                      csrQC, 512,
                                      ebufCQ, bbaseCQ, deg_CQ_dst, offsCQ,
                                      csrCQ);

  // 4. gathers (fp8 rows, half the bytes), split by relation
  gather_one<<<NQn / 4, 256, 0, stream>>>(xnbC, csrCQ, offsCQ, deg_CQ_dst,
                                          gate_CQ, msgQ);
  gather_one<<<NCn / 4, 256, 0, stream>>>(xnbQ, csrQC, offsQC, deg_QC_dst,
                                          gate_QC, msgC);

  // 5. merged fused MLP (R14-exact)
  mlp_fused2<<<NQn / 64 + NCn / 64, 256, 0, stream>>>(
      projQ, msgQ, W1Qt, b1_Q, W2Qt, b2_Q, outQ, NQn / 64,
      projC, msgC, W1Ct, b1_C, W2Ct, b2_C, outC);
}